// Round 6
// baseline (379.982 us; speedup 1.0000x reference)
//
#include <hip/hip_runtime.h>
#include <hip/hip_bf16.h>
#include <cstddef>
#include <cstdint>

// Problem constants (from reference)
#define NN 50000
#define MPAD 50048      // 391 tiles * 128
#define F_IN 128
#define NH 4
#define NC 64
#define NE 800000
#define NG 128
#define NOUT 8
#define HC 256          // NH*NC
#define EP (NE + NN)    // edges + self loops

typedef unsigned short ushort_t;
typedef _Float16 f16;
typedef __attribute__((ext_vector_type(2))) _Float16 f16x2;
typedef __attribute__((ext_vector_type(8))) _Float16 f16x8;
typedef __attribute__((ext_vector_type(4))) float f32x4;

// ---------------------------------------------------------------------------
// helpers
// ---------------------------------------------------------------------------
__device__ __forceinline__ float lrelu02(float x) { return x > 0.0f ? x : 0.2f * x; }
__device__ __forceinline__ float elu1(float x)    { return x > 0.0f ? x : expm1f(x); }

__device__ __forceinline__ ushort_t f2h_bits(float f) {
    f16 h = (f16)f;
    union { f16 h; ushort_t u; } cv; cv.h = h;
    return cv.u;
}
__device__ __forceinline__ uint32_t pack2h(float a, float b) {
    union { f16 h[2]; uint32_t u; } cv;
    cv.h[0] = (f16)a; cv.h[1] = (f16)b;
    return cv.u;
}
__device__ __forceinline__ f16x2 as_h2(uint32_t q) {
    union { uint32_t u; f16x2 h; } cv; cv.u = q;
    return cv.h;
}
__device__ __forceinline__ void h2_unpack(uint32_t q, float& lo, float& hi) {
    union { uint32_t u; f16 h[2]; } cv; cv.u = q;
    lo = (float)cv.h[0];
    hi = (float)cv.h[1];
}

// v_dot2_f32_f16: acc += a.h0*b.h0 + a.h1*b.h1 (f32 accumulate, full rate).
__device__ __forceinline__ float fdot2f(f16x2 a, f16x2 b, float c) {
#if __has_builtin(__builtin_amdgcn_fdot2)
    return __builtin_amdgcn_fdot2(a, b, c, false);
#else
    float d;
    asm("v_dot2_f32_f16 %0, %1, %2, %3" : "=v"(d) : "v"(a), "v"(b), "v"(c));
    return d;
#endif
}
__device__ __forceinline__ uint32_t permb(uint32_t a, uint32_t b, uint32_t s) {
    return __builtin_amdgcn_perm(a, b, s);
}
// v_perm selectors: bytes 0-3 = src1(b), bytes 4-7 = src0(a).
// SEL_E -> (a.h0, b.h0) ; SEL_O -> (a.h1, b.h1)
#define SEL_E 0x01000504u
#define SEL_O 0x03020706u

// async global -> LDS, 16B per lane; lds dest = wave-uniform base + lane*16
__device__ __forceinline__ void gld16(const void* g, void* l) {
    __builtin_amdgcn_global_load_lds(
        (const __attribute__((address_space(1))) unsigned int*)g,
        (__attribute__((address_space(3))) unsigned int*)l, 16, 0, 0);
}

// ---------------------------------------------------------------------------
// fused prep: edge histogram (rank-recording) + x->fp16 + W->fp16^T
// R18: atomicAdd's RETURN VALUE is the edge's rank within its dst bucket —
// stored to rank[] so edge_fill needs NO second atomic pass.
// ---------------------------------------------------------------------------
#define XN4 (NN * F_IN / 4)
#define NW (F_IN * HC + HC * HC)
__global__ void prep_kernel(const int* __restrict__ edst,
                            const float* __restrict__ x,
                            const float* __restrict__ W1,
                            const float* __restrict__ W2,
                            int* __restrict__ deg,
                            int* __restrict__ rank,
                            f16* __restrict__ xh,
                            f16* __restrict__ w1t, f16* __restrict__ w2t) {
    int idx = blockIdx.x * blockDim.x + threadIdx.x;
    if (idx < EP) {
        int d = (idx < NE) ? edst[idx] : (idx - NE);
        rank[idx] = atomicAdd(&deg[d], 1);
        return;
    }
    idx -= EP;
    if (idx < XN4) {
        float4 v = ((const float4*)x)[idx];
        f16 o[4] = {(f16)v.x, (f16)v.y, (f16)v.z, (f16)v.w};
        *(uint2*)(xh + idx * 4) = *(const uint2*)o;
        return;
    }
    idx -= XN4;
    const int n1 = F_IN * HC;
    if (idx < n1) {
        int k = idx / HC, n = idx % HC;
        w1t[n * F_IN + k] = (f16)W1[idx];
    } else if (idx < NW) {
        int i2 = idx - n1;
        int k = i2 / HC, n = i2 % HC;
        w2t[n * HC + k] = (f16)W2[i2];
    }
}

// ---------------------------------------------------------------------------
// CSR build: exclusive scan + fill (src ids, dst-sorted)
// ---------------------------------------------------------------------------
__global__ __launch_bounds__(256) void scan_p1(const int* __restrict__ deg,
                                               int* __restrict__ partials) {
    __shared__ int lds[256];
    int b = blockIdx.x, t = threadIdx.x;
    int i0 = b * 1024 + t * 4;
    int s = 0;
#pragma unroll
    for (int j = 0; j < 4; j++) { int i = i0 + j; if (i < NN) s += deg[i]; }
    lds[t] = s;
    __syncthreads();
    for (int o = 128; o; o >>= 1) { if (t < o) lds[t] += lds[t + o]; __syncthreads(); }
    if (t == 0) partials[b] = lds[0];
}

__global__ __launch_bounds__(256) void scan_p3(const int* __restrict__ deg,
                                               const int* __restrict__ partials,
                                               int* __restrict__ offs) {
    __shared__ int lds[256];
    __shared__ int base_s;
    int b = blockIdx.x, t = threadIdx.x;
    if (t == 0) {
        int s = 0;
        for (int i = 0; i < b; i++) s += partials[i];
        base_s = s;
        if (b == 0) offs[0] = 0;
    }
    int i0 = b * 1024 + t * 4;
    int v[4]; int s = 0;
#pragma unroll
    for (int j = 0; j < 4; j++) { int i = i0 + j; v[j] = (i < NN) ? deg[i] : 0; s += v[j]; }
    lds[t] = s;
    __syncthreads();
    for (int o = 1; o < 256; o <<= 1) {
        int x = (t >= o) ? lds[t - o] : 0;
        __syncthreads();
        lds[t] += x;
        __syncthreads();
    }
    int run = base_s + (lds[t] - s);
#pragma unroll
    for (int j = 0; j < 4; j++) { run += v[j]; int i = i0 + j; if (i < NN) offs[i + 1] = run; }
}

// R18: no atomics — rank precomputed in prep. Pure read + scatter.
__global__ void edge_fill(const int* __restrict__ esrc, const int* __restrict__ edst,
                          const int* __restrict__ offs, const int* __restrict__ rank,
                          int* __restrict__ csr) {
    int e = blockIdx.x * blockDim.x + threadIdx.x;
    if (e >= EP) return;
    int s, d;
    if (e < NE) { s = esrc[e]; d = edst[e]; } else { s = d = e - NE; }
    csr[offs[d] + rank[e]] = s;
}

// ---------------------------------------------------------------------------
// fp16 MFMA GEMM, fused GAT epilogue (R10 shape, BK=32).
// hf2 dword layout [node][by*64+c]: dword = (hi: head 2by+1, lo: head 2by)
// packed fp16 for channel c (contiguous 256B/row per block).
// ---------------------------------------------------------------------------
__global__ __launch_bounds__(256, 3) void gemm_gat(
        const f16* __restrict__ A, const f16* __restrict__ BT,
        const float* __restrict__ a_s, const float* __restrict__ a_d,
        ushort_t* __restrict__ hf2, float* __restrict__ asrc,
        float* __restrict__ adst, int M, int K) {
    __shared__ alignas(16) char smem[33792];   // staging 16KB / repack 33.8KB
    f16* lA = (f16*)smem;            // [128 rows][32 k]
    f16* lB = (f16*)smem + 4096;     // [128 rows][32 k]

    int t = threadIdx.x;
    int wave = t >> 6, lane = t & 63;
    int wm = wave >> 1, wn = wave & 1;
    int quad = lane >> 4, l15 = lane & 15;
    int tileM = blockIdx.x * 128;
    int by = blockIdx.y;

    f32x4 acc[4][4];
#pragma unroll
    for (int f = 0; f < 4; f++)
#pragma unroll
        for (int g = 0; g < 4; g++) acc[f][g] = (f32x4){0.f, 0.f, 0.f, 0.f};

    for (int k0 = 0; k0 < K; k0 += 32) {
        __syncthreads();
#pragma unroll
        for (int i = 0; i < 2; i++) {
            int c = wave * 2 + i;
            int row = c * 16 + (lane >> 2);
            int kk = k0 + (lane & 3) * 8;
            gld16(A + (size_t)(tileM + row) * K + kk, &lA[c * 512]);
            gld16(BT + (size_t)(by * 128 + row) * K + kk, &lB[c * 512]);
        }
        __syncthreads();

        f16x8 ah[4], bh[4];
#pragma unroll
        for (int f = 0; f < 4; f++)
            ah[f] = *(const f16x8*)&lA[(wm * 64 + f * 16 + l15) * 32 + quad * 8];
#pragma unroll
        for (int g = 0; g < 4; g++)
            bh[g] = *(const f16x8*)&lB[(wn * 64 + g * 16 + l15) * 32 + quad * 8];
#pragma unroll
        for (int f = 0; f < 4; f++)
#pragma unroll
            for (int g = 0; g < 4; g++)
                acc[f][g] = __builtin_amdgcn_mfma_f32_16x16x32_f16(ah[f], bh[g], acc[f][g], 0, 0, 0);
    }

    // ---- epilogue 1: per-head attention dots (this wave's 64 cols = 1 head)
    int head = (by << 1) | wn;
    float as_v[4], ad_v[4];
#pragma unroll
    for (int g = 0; g < 4; g++) {
        as_v[g] = a_s[head * 64 + g * 16 + l15];
        ad_v[g] = a_d[head * 64 + g * 16 + l15];
    }
#pragma unroll
    for (int f = 0; f < 4; f++) {
#pragma unroll
        for (int r = 0; r < 4; r++) {
            float ps = acc[f][0][r] * as_v[0] + acc[f][1][r] * as_v[1]
                     + acc[f][2][r] * as_v[2] + acc[f][3][r] * as_v[3];
            float pd = acc[f][0][r] * ad_v[0] + acc[f][1][r] * ad_v[1]
                     + acc[f][2][r] * ad_v[2] + acc[f][3][r] * ad_v[3];
#pragma unroll
            for (int o = 1; o < 16; o <<= 1) {
                ps += __shfl_xor(ps, o);
                pd += __shfl_xor(pd, o);
            }
            int row = tileM + wm * 64 + f * 16 + quad * 4 + r;
            if (l15 == 0 && row < M) {
                asrc[row * 4 + head] = ps;
                adst[row * 4 + head] = pd;
            }
        }
    }

    // ---- epilogue 2: packed fp16 tile via padded LDS repack.
    __syncthreads();   // K-loop staging LDS dead
    ushort_t* lC2u = (ushort_t*)smem;
    const uint32_t* lC2d = (const uint32_t*)smem;
#pragma unroll
    for (int f = 0; f < 4; f++)
#pragma unroll
        for (int g = 0; g < 4; g++)
#pragma unroll
            for (int r = 0; r < 4; r++)
                lC2u[(wm * 64 + f * 16 + quad * 4 + r) * 132 + (g * 16 + l15) * 2 + wn] =
                    f2h_bits(acc[f][g][r]);
    __syncthreads();
    uint32_t* hb2 = (uint32_t*)hf2;
#pragma unroll
    for (int it = 0; it < 32; it++) {
        int row = wave * 32 + it;
        uint32_t v = lC2d[row * 66 + lane];
        hb2[(size_t)(tileM + row) * 128 + by * 64 + lane] = v;
    }
}

// ---------------------------------------------------------------------------
// Full-wave-per-node fallback (rare: any node in the wave's pair with deg>32).
// R18: CONCAT=0 ending goes straight to pool atomics (of == pool), no bias.
// ---------------------------------------------------------------------------
template <int CONCAT>
__device__ void gat_node_fullwave(const ushort_t* __restrict__ hf2,
                                  const float* __restrict__ asrc,
                                  const float* __restrict__ adst,
                                  const int* __restrict__ offs,
                                  const int* __restrict__ csr,
                                  const int* __restrict__ gb,
                                  const float* __restrict__ bias,
                                  f16* __restrict__ oh,
                                  float* __restrict__ of,
                                  int node, int lane, uint2* lwF) {
    int start = offs[node];
    int deg = offs[node + 1] - start;
    float4 ad = *(const float4*)(adst + node * 4);

    float w0, w1, w2, w3;
    float m0, m1, m2, m3, i0, i1, i2, i3;
    int msrc = 0;

    if (deg <= 64) {
        float t0 = -1e30f, t1 = -1e30f, t2 = -1e30f, t3 = -1e30f;
        if (lane < deg) {
            int sidx = csr[start + lane];
            float4 as = *(const float4*)(asrc + sidx * 4);
            t0 = lrelu02(as.x + ad.x);
            t1 = lrelu02(as.y + ad.y);
            t2 = lrelu02(as.z + ad.z);
            t3 = lrelu02(as.w + ad.w);
            msrc = sidx;
        }
        m0 = t0; m1 = t1; m2 = t2; m3 = t3;
#pragma unroll
        for (int o = 1; o < 64; o <<= 1) {
            m0 = fmaxf(m0, __shfl_xor(m0, o));
            m1 = fmaxf(m1, __shfl_xor(m1, o));
            m2 = fmaxf(m2, __shfl_xor(m2, o));
            m3 = fmaxf(m3, __shfl_xor(m3, o));
        }
        w0 = __expf(t0 - m0);
        w1 = __expf(t1 - m1);
        w2 = __expf(t2 - m2);
        w3 = __expf(t3 - m3);
        float s0 = w0, s1 = w1, s2 = w2, s3 = w3;
#pragma unroll
        for (int o = 1; o < 64; o <<= 1) {
            s0 += __shfl_xor(s0, o);
            s1 += __shfl_xor(s1, o);
            s2 += __shfl_xor(s2, o);
            s3 += __shfl_xor(s3, o);
        }
        i0 = 1.0f / (s0 + 1e-16f);
        i1 = 1.0f / (s1 + 1e-16f);
        i2 = 1.0f / (s2 + 1e-16f);
        i3 = 1.0f / (s3 + 1e-16f);
        w0 *= i0; w1 *= i1; w2 *= i2; w3 *= i3;
    } else {
        m0 = m1 = m2 = m3 = -1e30f;
        float s0 = 0.f, s1 = 0.f, s2 = 0.f, s3 = 0.f;
        float e0 = 0.f, e1 = 0.f, e2 = 0.f, e3 = 0.f;
        for (int j = lane; j < deg; j += 64) {
            int sidx = csr[start + j];
            float4 as = *(const float4*)(asrc + sidx * 4);
            float t0 = lrelu02(as.x + ad.x);
            float t1 = lrelu02(as.y + ad.y);
            float t2 = lrelu02(as.z + ad.z);
            float t3 = lrelu02(as.w + ad.w);
            if (j == lane) { e0 = t0; e1 = t1; e2 = t2; e3 = t3; msrc = sidx; }
            float nm;
            nm = fmaxf(m0, t0); s0 = s0 * __expf(m0 - nm) + __expf(t0 - nm); m0 = nm;
            nm = fmaxf(m1, t1); s1 = s1 * __expf(m1 - nm) + __expf(t1 - nm); m1 = nm;
            nm = fmaxf(m2, t2); s2 = s2 * __expf(m2 - nm) + __expf(t2 - nm); m2 = nm;
            nm = fmaxf(m3, t3); s3 = s3 * __expf(m3 - nm) + __expf(t3 - nm); m3 = nm;
        }
        for (int o = 32; o; o >>= 1) {
            float om, os, nm;
            om = __shfl_xor(m0, o); os = __shfl_xor(s0, o);
            nm = fmaxf(m0, om); s0 = s0 * __expf(m0 - nm) + os * __expf(om - nm); m0 = nm;
            om = __shfl_xor(m1, o); os = __shfl_xor(s1, o);
            nm = fmaxf(m1, om); s1 = s1 * __expf(m1 - nm) + os * __expf(om - nm); m1 = nm;
            om = __shfl_xor(m2, o); os = __shfl_xor(s2, o);
            nm = fmaxf(m2, om); s2 = s2 * __expf(m2 - nm) + os * __expf(om - nm); m2 = nm;
            om = __shfl_xor(m3, o); os = __shfl_xor(s3, o);
            nm = fmaxf(m3, om); s3 = s3 * __expf(m3 - nm) + os * __expf(om - nm); m3 = nm;
        }
        i0 = 1.0f / (s0 + 1e-16f);
        i1 = 1.0f / (s1 + 1e-16f);
        i2 = 1.0f / (s2 + 1e-16f);
        i3 = 1.0f / (s3 + 1e-16f);
        w0 = __expf(e0 - m0) * i0;
        w1 = __expf(e1 - m1) * i1;
        w2 = __expf(e2 - m2) * i2;
        w3 = __expf(e3 - m3) * i3;
    }

    lwF[lane] = (uint2){pack2h(w0, w1), pack2h(w2, w3)};

    int hp = lane >> 5;
    const uint32_t* lwu = (const uint32_t*)lwF;
    float aE0 = 0.f, aO0 = 0.f, aE1 = 0.f, aO1 = 0.f;
    float c0a = 0.f, c0b = 0.f, c1a = 0.f, c1b = 0.f;
    const uint32_t* hb = (const uint32_t*)hf2 + lane * 2;
    int jmax = deg < 64 ? deg : 64;

    int j = 0;
    if (CONCAT) {
        for (; j + 4 <= jmax; j += 4) {
            int s0 = __builtin_amdgcn_readlane(msrc, j);
            int s1 = __builtin_amdgcn_readlane(msrc, j + 1);
            int s2 = __builtin_amdgcn_readlane(msrc, j + 2);
            int s3 = __builtin_amdgcn_readlane(msrc, j + 3);
            uint2 q0 = *(const uint2*)(hb + (size_t)s0 * 128);
            uint2 q1 = *(const uint2*)(hb + (size_t)s1 * 128);
            uint2 q2 = *(const uint2*)(hb + (size_t)s2 * 128);
            uint2 q3 = *(const uint2*)(hb + (size_t)s3 * 128);
            uint32_t wA = lwu[(j + 0) * 2 + hp];
            uint32_t wB = lwu[(j + 1) * 2 + hp];
            uint32_t wC = lwu[(j + 2) * 2 + hp];
            uint32_t wD = lwu[(j + 3) * 2 + hp];
            uint32_t weAB = permb(wA, wB, SEL_E), woAB = permb(wA, wB, SEL_O);
            uint32_t weCD = permb(wC, wD, SEL_E), woCD = permb(wC, wD, SEL_O);
            uint32_t xeAB = permb(q0.x, q1.x, SEL_E), xoAB = permb(q0.x, q1.x, SEL_O);
            uint32_t yeAB = permb(q0.y, q1.y, SEL_E), yoAB = permb(q0.y, q1.y, SEL_O);
            uint32_t xeCD = permb(q2.x, q3.x, SEL_E), xoCD = permb(q2.x, q3.x, SEL_O);
            uint32_t yeCD = permb(q2.y, q3.y, SEL_E), yoCD = permb(q2.y, q3.y, SEL_O);
            aE0 = fdot2f(as_h2(xeAB), as_h2(weAB), aE0);
            aO0 = fdot2f(as_h2(xoAB), as_h2(woAB), aO0);
            aE1 = fdot2f(as_h2(yeAB), as_h2(weAB), aE1);
            aO1 = fdot2f(as_h2(yoAB), as_h2(woAB), aO1);
            aE0 = fdot2f(as_h2(xeCD), as_h2(weCD), aE0);
            aO0 = fdot2f(as_h2(xoCD), as_h2(woCD), aO0);
            aE1 = fdot2f(as_h2(yeCD), as_h2(weCD), aE1);
            aO1 = fdot2f(as_h2(yoCD), as_h2(woCD), aO1);
        }
        for (; j < jmax; j++) {
            int sidx = __builtin_amdgcn_readlane(msrc, j);
            f16x2 wh = as_h2(lwu[j * 2 + hp]);
            uint2 q = *(const uint2*)(hb + (size_t)sidx * 128);
            f16x2 qx = as_h2(q.x), qy = as_h2(q.y);
            aE0 += (float)qx[0] * (float)wh[0];
            aO0 += (float)qx[1] * (float)wh[1];
            aE1 += (float)qy[0] * (float)wh[0];
            aO1 += (float)qy[1] * (float)wh[1];
        }
    } else {
        for (; j + 4 <= jmax; j += 4) {
            int s0 = __builtin_amdgcn_readlane(msrc, j);
            int s1 = __builtin_amdgcn_readlane(msrc, j + 1);
            int s2 = __builtin_amdgcn_readlane(msrc, j + 2);
            int s3 = __builtin_amdgcn_readlane(msrc, j + 3);
            uint2 q0 = *(const uint2*)(hb + (size_t)s0 * 128);
            uint2 q1 = *(const uint2*)(hb + (size_t)s1 * 128);
            uint2 q2 = *(const uint2*)(hb + (size_t)s2 * 128);
            uint2 q3 = *(const uint2*)(hb + (size_t)s3 * 128);
            f16x2 w0v = as_h2(lwu[(j + 0) * 2 + hp]);
            f16x2 w1v = as_h2(lwu[(j + 1) * 2 + hp]);
            f16x2 w2v = as_h2(lwu[(j + 2) * 2 + hp]);
            f16x2 w3v = as_h2(lwu[(j + 3) * 2 + hp]);
            c0a = fdot2f(as_h2(q0.x), w0v, c0a);
            c1a = fdot2f(as_h2(q0.y), w0v, c1a);
            c0b = fdot2f(as_h2(q1.x), w1v, c0b);
            c1b = fdot2f(as_h2(q1.y), w1v, c1b);
            c0a = fdot2f(as_h2(q2.x), w2v, c0a);
            c1a = fdot2f(as_h2(q2.y), w2v, c1a);
            c0b = fdot2f(as_h2(q3.x), w3v, c0b);
            c1b = fdot2f(as_h2(q3.y), w3v, c1b);
        }
        for (; j < jmax; j++) {
            int sidx = __builtin_amdgcn_readlane(msrc, j);
            f16x2 wh = as_h2(lwu[j * 2 + hp]);
            uint2 q = *(const uint2*)(hb + (size_t)sidx * 128);
            c0a = fdot2f(as_h2(q.x), wh, c0a);
            c1a = fdot2f(as_h2(q.y), wh, c1a);
        }
    }
    for (int jj = 64; jj < deg; jj++) {
        int sidx = csr[start + jj];
        float4 as = *(const float4*)(asrc + sidx * 4);
        float u0 = __expf(lrelu02(as.x + ad.x) - m0) * i0;
        float u1 = __expf(lrelu02(as.y + ad.y) - m1) * i1;
        float u2 = __expf(lrelu02(as.z + ad.z) - m2) * i2;
        float u3 = __expf(lrelu02(as.w + ad.w) - m3) * i3;
        float ue = hp ? u2 : u0;
        float uo = hp ? u3 : u1;
        uint2 q = *(const uint2*)(hb + (size_t)sidx * 128);
        float xl, xh2, yl, yh;
        h2_unpack(q.x, xl, xh2);
        h2_unpack(q.y, yl, yh);
        if (CONCAT) {
            aE0 += ue * xl;
            aO0 += uo * xh2;
            aE1 += ue * yl;
            aO1 += uo * yh;
        } else {
            c0a += ue * xl + uo * xh2;
            c1a += ue * yl + uo * yh;
        }
    }

    int c0 = (lane & 31) * 2;
    int he = hp * 2, ho = hp * 2 + 1;
    if (CONCAT) {
        size_t base = (size_t)node * HC;
        float vE0 = elu1(aE0 + bias[he * 64 + c0]);
        float vE1 = elu1(aE1 + bias[he * 64 + c0 + 1]);
        float vO0 = elu1(aO0 + bias[ho * 64 + c0]);
        float vO1 = elu1(aO1 + bias[ho * 64 + c0 + 1]);
        f16 pe[2] = {(f16)vE0, (f16)vE1};
        f16 po[2] = {(f16)vO0, (f16)vO1};
        *(uint32_t*)(oh + base + he * 64 + c0) = *(const uint32_t*)pe;
        *(uint32_t*)(oh + base + ho * 64 + c0) = *(const uint32_t*)po;
    } else {
        float s0 = c0a + c0b;
        float s1 = c1a + c1b;
        s0 += __shfl_xor(s0, 32);
        s1 += __shfl_xor(s1, 32);
        if (hp == 0) {
            int g = gb[node];
            atomicAdd(of + g * 64 + c0, 0.25f * s0);
            atomicAdd(of + g * 64 + c0 + 1, 0.25f * s1);
        }
    }
}

// ---------------------------------------------------------------------------
// GAT aggregation R18: two nodes/wave, double-buffered pipeline (R17), plus:
// CONCAT=0 fuses the global-mean-pool — hp0 lanes atomicAdd 0.25*s directly
// into pool[g*64+c] (of == pool). The wave's two nodes usually share a graph
// (sorted batch, ~390 nodes/graph): cross-group shfl(32) combines them into
// ONE atomic set per wave (~1.6M atomics over 8192 addrs ~ 200/addr, spread).
// Bias + /cnt move to fc (mean(s+b) == mean(s)+b). Kills pool_kernel and the
// out2 12.8MB write + 12.8MB read.
// ---------------------------------------------------------------------------
template <int CONCAT>
__global__ __launch_bounds__(256, 4) void gat_agg(const ushort_t* __restrict__ hf2,
                                                  const float* __restrict__ asrc,
                                                  const float* __restrict__ adst,
                                                  const int* __restrict__ offs,
                                                  const int* __restrict__ csr,
                                                  const int* __restrict__ gb,
                                                  const float* __restrict__ bias,
                                                  f16* __restrict__ oh,
                                                  float* __restrict__ of) {
    __shared__ uint4 lw4[4][64];   // [wave][grp*32 + j] = {src, w01, src, w23}
    int wave = threadIdx.x >> 6, lane = threadIdx.x & 63;
    int grp = lane >> 5, l31 = lane & 31;
    int hp = (lane >> 4) & 1;      // head pair within group
    int nbase = blockIdx.x * 8 + wave * 2;   // NN % 8 == 0: always in range
    int node = nbase + grp;
    int start = offs[node];
    int deg = offs[node + 1] - start;

    if (!__all(deg <= 32)) {
        // rare fallback: full wave per node, sequentially
        uint2* lwF = (uint2*)&lw4[wave][0];
        gat_node_fullwave<CONCAT>(hf2, asrc, adst, offs, csr, gb, bias, oh, of,
                                  nbase, lane, lwF);
        gat_node_fullwave<CONCAT>(hf2, asrc, adst, offs, csr, gb, bias, oh, of,
                                  nbase + 1, lane, lwF);
        return;
    }

    // ---------- prologue: csr read, then EARLY batch-0/1 row loads ----------
    const uint4* hq = (const uint4*)hf2;   // hf2 row = 32 uint4
    int msrc = 0;
    bool act = l31 < deg;
    if (act) msrc = csr[start + l31];

    int b0 = grp * 32;
    int i0 = __shfl(msrc, b0 + 0);
    int i1 = __shfl(msrc, b0 + 1);
    int i2 = __shfl(msrc, b0 + 2);
    int i3 = __shfl(msrc, b0 + 3);
    int i4 = __shfl(msrc, b0 + 4);
    int i5 = __shfl(msrc, b0 + 5);
    int i6 = __shfl(msrc, b0 + 6);
    int i7 = __shfl(msrc, b0 + 7);
    uint4 q0 = hq[(uint32_t)i0 * 32u + l31];
    uint4 q1 = hq[(uint32_t)i1 * 32u + l31];
    uint4 q2 = hq[(uint32_t)i2 * 32u + l31];
    uint4 q3 = hq[(uint32_t)i3 * 32u + l31];
    uint4 r0 = hq[(uint32_t)i4 * 32u + l31];
    uint4 r1 = hq[(uint32_t)i5 * 32u + l31];
    uint4 r2 = hq[(uint32_t)i6 * 32u + l31];
    uint4 r3 = hq[(uint32_t)i7 * 32u + l31];

    // ---------- softmax over the 32-lane group (deg <= 32) ----------
    float4 ad = *(const float4*)(adst + (size_t)node * 4);
    float t0 = -1e30f, t1 = -1e30f, t2 = -1e30f, t3 = -1e30f;
    if (act) {
        float4 as = *(const float4*)(asrc + (size_t)msrc * 4);
        t0 = lrelu02(as.x + ad.x);
        t1 = lrelu02(as.y + ad.y);
        t2 = lrelu02(as.z + ad.z);
        t3 = lrelu02(as.w + ad.w);
    }
    float m0 = t0, m1 = t1, m2 = t2, m3 = t3;
#pragma unroll
    for (int o = 1; o < 32; o <<= 1) {
        m0 = fmaxf(m0, __shfl_xor(m0, o));
        m1 = fmaxf(m1, __shfl_xor(m1, o));
        m2 = fmaxf(m2, __shfl_xor(m2, o));
        m3 = fmaxf(m3, __shfl_xor(m3, o));
    }
    float w0 = __expf(t0 - m0);
    float w1 = __expf(t1 - m1);
    float w2 = __expf(t2 - m2);
    float w3 = __expf(t3 - m3);
    float s0 = w0, s1 = w1, s2 = w2, s3 = w3;
#pragma unroll
    for (int o = 1; o < 32; o <<= 1) {
        s0 += __shfl_xor(s0, o);
        s1 += __shfl_xor(s1, o);
        s2 += __shfl_xor(s2, o);
        s3 += __shfl_xor(s3, o);
    }
    w0 *= 1.0f / (s0 + 1e-16f);
    w1 *= 1.0f / (s1 + 1e-16f);
    w2 *= 1.0f / (s2 + 1e-16f);
    w3 *= 1.0f / (s3 + 1e-16f);

    // park per-edge entry (wave-private LDS; no barrier). pad lanes: w=0.
    lw4[wave][lane] = (uint4){(uint32_t)msrc, pack2h(w0, w1),
                              (uint32_t)msrc, pack2h(w2, w3)};

    const uint2* lwp = (const uint2*)&lw4[wave][grp * 32];  // entry j half hp
    int c0 = (l31 & 15) * 4;
    int deg4 = (deg + 3) & ~3;     // >= 4 (self-loop guarantees deg >= 1)

    // weights for batches 0 (q) and 1 (r), this lane's head pair
    uint32_t wy0 = lwp[0 * 2 + hp].y;
    uint32_t wy1 = lwp[1 * 2 + hp].y;
    uint32_t wy2 = lwp[2 * 2 + hp].y;
    uint32_t wy3 = lwp[3 * 2 + hp].y;
    uint32_t wz0 = lwp[4 * 2 + hp].y;
    uint32_t wz1 = lwp[5 * 2 + hp].y;
    uint32_t wz2 = lwp[6 * 2 + hp].y;
    uint32_t wz3 = lwp[7 * 2 + hp].y;

    if (CONCAT) {
        float aE0 = 0.f, aE1 = 0.f, aE2 = 0.f, aE3 = 0.f;
        float aO0 = 0.f, aO1 = 0.f, aO2 = 0.f, aO3 = 0.f;
#define CPAIR(A0, A1, W0, W1)                                                  \
        {                                                                      \
            uint32_t we = permb(W0, W1, SEL_E);                                \
            uint32_t wo = permb(W0, W1, SEL_O);                                \
            aE0 = fdot2f(as_h2(permb(A0.x, A1.x, SEL_E)), as_h2(we), aE0);     \
            aO0 = fdot2f(as_h2(permb(A0.x, A1.x, SEL_O)), as_h2(wo), aO0);     \
            aE1 = fdot2f(as_h2(permb(A0.y, A1.y, SEL_E)), as_h2(we), aE1);     \
            aO1 = fdot2f(as_h2(permb(A0.y, A1.y, SEL_O)), as_h2(wo), aO1);     \
            aE2 = fdot2f(as_h2(permb(A0.z, A1.z, SEL_E)), as_h2(we), aE2);     \
            aO2 = fdot2f(as_h2(permb(A0.z, A1.z, SEL_O)), as_h2(wo), aO2);     \
            aE3 = fdot2f(as_h2(permb(A0.w, A1.w, SEL_E)), as_h2(we), aE3);     \
            aO3 = fdot2f(as_h2(permb(A0.w, A1.w, SEL_O)), as_h2(wo), aO3);     \
        }
        int j = 0;
        for (;;) {
            // ---- compute q batch (edges j..j+3), prefetch j+8..j+11 -> q ----
            CPAIR(q0, q1, wy0, wy1)
            CPAIR(q2, q3, wy2, wy3)
            {
                int p = j + 8;
                if (p < deg4) {
                    uint2 n0 = lwp[(p + 0) * 2 + hp];
                    uint2 n1 = lwp[(p + 1) * 2 + hp];
                    uint2 n2 = lwp[(p + 2) * 2 + hp];
                    uint2 n3 = lwp[(p + 3) * 2 + hp];
                    wy0 = n0.y; wy1 = n1.y; wy2 = n2.y; wy3 = n3.y;
                    q0 = hq[n0.x * 32u + l31];
                    q1 = hq[n1.x * 32u + l31];
                    q2 = hq[n2.x * 32u + l31];
                    q3 = hq[n3.x * 32u + l31];
                }
            }
            j += 4;
            if (j >= deg4) break;
            // ---- compute r batch (edges j..j+3), prefetch j+8..j+11 -> r ----
            CPAIR(r0, r1, wz0, wz1)
            CPAIR(r2, r3, wz2, wz3)
            {
                int p = j + 8;
                if (p < deg4) {
                    uint2 n0 = lwp[(p + 0) * 2 + hp];
                    uint2 n1 = lwp[(p + 1) * 2 + hp];
                    uint2 n2 = lwp[(p + 2) * 2 + hp];
                    uint2 n3 = lwp[(p + 3) * 2 + hp];
                    wz0 = n0.y; wz1 = n1.y; wz2 = n2.y; wz3 = n3.y;
                    r0 = hq[n0.x * 32u + l31];
                    r1 = hq[n1.x * 32u + l31];
                    r2 = hq[n2.x * 32u + l31];
                    r3 = hq[n3.x * 32u + l31];
                }
            }
            j += 4;
            if (j >= deg4) break;
        }
#undef CPAIR
        // heads stay separate: lane writes 4 channels x (even,odd) heads
        int he = hp * 2, ho = hp * 2 + 1;
        size_t base = (size_t)node * HC;
        float4 bE = *(const float4*)(bias + he * 64 + c0);
        float4 bO = *(const float4*)(bias + ho * 64 + c0);
        f16 pe[4] = {(f16)elu1(aE0 + bE.x), (f16)elu1(aE1 + bE.y),
                     (f16)elu1(aE2 + bE.z), (f16)elu1(aE3 + bE.w)};
        f16 po[4] = {(f16)elu1(aO0 + bO.x), (f16)elu1(aO1 + bO.y),
                     (f16)elu1(aO2 + bO.z), (f16)elu1(aO3 + bO.w)};
        *(uint2*)(oh + base + he * 64 + c0) = *(const uint2*)pe;
        *(uint2*)(oh + base + ho * 64 + c0) = *(const uint2*)po;
    } else {
        float a0 = 0.f, a1 = 0.f, a2 = 0.f, a3 = 0.f;
        float b0f = 0.f, b1f = 0.f, b2f = 0.f, b3f = 0.f;
        int j = 0;
        for (;;) {
            // ---- compute q batch, prefetch j+8 -> q ----
            {
                f16x2 wvA = as_h2(wy0), wvB = as_h2(wy1);
                f16x2 wvC = as_h2(wy2), wvD = as_h2(wy3);
                a0 = fdot2f(as_h2(q0.x), wvA, a0);
                a1 = fdot2f(as_h2(q0.y), wvA, a1);
                a2 = fdot2f(as_h2(q0.z), wvA, a2);
                a3 = fdot2f(as_h2(q0.w), wvA, a3);
                b0f = fdot2f(as_h2(q1.x), wvB, b0f);
                b1f = fdot2f(as_h2(q1.y), wvB, b1f);
                b2f = fdot2f(as_h2(q1.z), wvB, b2f);
                b3f = fdot2f(as_h2(q1.w), wvB, b3f);
                a0 = fdot2f(as_h2(q2.x), wvC, a0);
                a1 = fdot2f(as_h2(q2.y), wvC, a1);
                a2 = fdot2f(as_h2(q2.z), wvC, a2);
                a3 = fdot2f(as_h2(q2.w), wvC, a3);
                b0f = fdot2f(as_h2(q3.x), wvD, b0f);
                b1f = fdot2f(as_h2(q3.y), wvD, b1f);
                b2f = fdot2f(as_h2(q3.z), wvD, b2f);
                b3f = fdot2f(as_h2(q3.w), wvD, b3f);
            }
            {
                int p = j + 8;
                if (p < deg4) {
                    uint2 n0 = lwp[(p + 0) * 2 + hp];
                    uint2 n1 = lwp[(p + 1) * 2 + hp];
                    uint2 n2 = lwp[(p + 2) * 2 + hp];
                    uint2 n3 = lwp[(p + 3) * 2 + hp];
                    wy0 = n0.y; wy1 = n1.y; wy2 = n2.y; wy3 = n3.y;
                    q0 = hq[n0.x * 32u + l31];
                    q1 = hq[n1.x * 32u + l31];
                    q2 = hq[n2.x * 32u + l31];
                    q3 = hq[n3.x * 32u + l31];
                }
            }
            j += 4;
            if (j >= deg4) break;
            // ---- compute r batch, prefetch j+8 -> r ----
            {
                f16x2 wvA = as_h2(wz0), wvB = as_h2(wz1);
                f16x2 wvC = as_h2(wz2), wvD = as_h2(wz3);
                a0 = fdot2f(as_h2(r0.x), wvA, a0);
                a1 = fdot2f(as_h2(r0.y), wvA, a1);
                a2 = fdot2f(as_h2(r0.z), wvA, a2);
                a3 = fdot2f(as_h2(r0.w), wvA, a3);
                b0f = fdot2f(as_h2(r1.x), wvB, b0f);
                b1f = fdot2f(as_h2(r1.y), wvB, b1f);
                b2f = fdot2f(as_h2(r1.z), wvB, b2f);
                b3f = fdot2f(as_h2(r1.w), wvB, b3f);
                a0 = fdot2f(as_h2(r2.x), wvC, a0);
                a1 = fdot2f(as_h2(r2.y), wvC, a1);
                a2 = fdot2f(as_h2(r2.z), wvC, a2);
                a3 = fdot2f(as_h2(r2.w), wvC, a3);
                b0f = fdot2f(as_h2(r3.x), wvD, b0f);
                b1f = fdot2f(as_h2(r3.y), wvD, b1f);
                b2f = fdot2f(as_h2(r3.z), wvD, b2f);
                b3f = fdot2f(as_h2(r3.w), wvD, b3f);
            }
            {
                int p = j + 8;
                if (p < deg4) {
                    uint2 n0 = lwp[(p + 0) * 2 + hp];
                    uint2 n1 = lwp[(p + 1) * 2 + hp];
                    uint2 n2 = lwp[(p + 2) * 2 + hp];
                    uint2 n3 = lwp[(p + 3) * 2 + hp];
                    wz0 = n0.y; wz1 = n1.y; wz2 = n2.y; wz3 = n3.y;
                    r0 = hq[n0.x * 32u + l31];
                    r1 = hq[n1.x * 32u + l31];
                    r2 = hq[n2.x * 32u + l31];
                    r3 = hq[n3.x * 32u + l31];
                }
            }
            j += 4;
            if (j >= deg4) break;
        }
        // head-pair sum is in each dot2; add the other hp via shfl_xor(16)
        float u0 = a0 + b0f, u1 = a1 + b1f, u2 = a2 + b2f, u3 = a3 + b3f;
        u0 += __shfl_xor(u0, 16);
        u1 += __shfl_xor(u1, 16);
        u2 += __shfl_xor(u2, 16);
        u3 += __shfl_xor(u3, 16);
        // ---- fused mean-pool: atomics into pool[g*64+c] (of == pool) ----
        float o0 = 0.25f * u0, o1 = 0.25f * u1, o2 = 0.25f * u2, o3 = 0.25f * u3;
        float p0 = __shfl_xor(o0, 32);
        float p1 = __shfl_xor(o1, 32);
        float p2 = __shfl_xor(o2, 32);
        float p3 = __shfl_xor(o3, 32);
        int g = gb[node];
        int gO = __shfl_xor(g, 32);
        if (hp == 0) {
            float* pb = of + g * 64 + c0;
            if (g == gO) {
                if (grp == 0) {   // one group carries both nodes' sums
                    atomicAdd(pb + 0, o0 + p0);
                    atomicAdd(pb + 1, o1 + p1);
                    atomicAdd(pb + 2, o2 + p2);
                    atomicAdd(pb + 3, o3 + p3);
                }
            } else {
                atomicAdd(pb + 0, o0);
                atomicAdd(pb + 1, o1);
                atomicAdd(pb + 2, o2);
                atomicAdd(pb + 3, o3);
            }
        }
    }
}

// ---------------------------------------------------------------------------
// fc: cnt via binary search over the SORTED batch (no atomics, no pool pass);
// bias b2 folded in here: pooled_c = pool[g][c]/cnt + b2[c].
// ---------------------------------------------------------------------------
__global__ void fc_kernel(const float* __restrict__ pool,
                          const int* __restrict__ batch,
                          const float* __restrict__ b2,
                          const float* __restrict__ fc_w, const float* __restrict__ fc_b,
                          float* __restrict__ out) {
    int idx = blockIdx.x * blockDim.x + threadIdx.x;
    if (idx >= NG * NOUT) return;
    int g = idx >> 3, o = idx & 7;
    int lo = 0, hi = NN;
    while (lo < hi) { int mid = (lo + hi) >> 1; if (batch[mid] < g) lo = mid + 1; else hi = mid; }
    int lo2 = lo, hi2 = NN;
    while (lo2 < hi2) { int mid = (lo2 + hi2) >> 1; if (batch[mid] < g + 1) lo2 = mid + 1; else hi2 = mid; }
    float inv = 1.0f / fmaxf((float)(lo2 - lo), 1.0f);
    float s = 0.f;
#pragma unroll
    for (int c = 0; c < 64; c++)
        s += (pool[g * 64 + c] * inv + b2[c]) * fc_w[c * 8 + o];
    out[idx] = s + fc_b[o];
}

// ---------------------------------------------------------------------------
extern "C" void kernel_launch(void* const* d_in, const int* in_sizes, int n_in,
                              void* d_out, int out_size, void* d_ws, size_t ws_size,
                              hipStream_t stream) {
    const float* x    = (const float*)d_in[0];
    const int*   ei   = (const int*)d_in[1];   // [2, E]
    const int*   batch= (const int*)d_in[2];
    const float* W1   = (const float*)d_in[3];
    const float* a1s  = (const float*)d_in[4];
    const float* a1d  = (const float*)d_in[5];
    const float* b1   = (const float*)d_in[6];
    const float* W2   = (const float*)d_in[7];
    const float* a2s  = (const float*)d_in[8];
    const float* a2d  = (const float*)d_in[9];
    const float* b2   = (const float*)d_in[10];
    const float* fc_w = (const float*)d_in[11];
    const float* fc_b = (const float*)d_in[12];
    float* out = (float*)d_out;

    char* p = (char*)d_ws;
    auto alloc = [&](size_t bytes) -> char* {
        char* r = p; p += (bytes + 255) & ~(size_t)255; return r;
    };
    int*   deg     = (int*)alloc((size_t)NN * 4);
    float* pool    = (float*)alloc((size_t)NG * 64 * 4);
    size_t zero_bytes = (size_t)(p - (char*)d_ws);
    int*   offs    = (int*)alloc((size_t)(NN + 1) * 4);
    int*   partials= (int*)alloc(64 * 4);
    int*   csr     = (int*)alloc((size_t)EP * 4);
    int*   rank    = (int*)alloc((size_t)EP * 4);
    float* asrc    = (float*)alloc((size_t)NN * 4 * 4);
    float* adst    = (float*)alloc((size_t)NN * 4 * 4);
    ushort_t* hf2  = (ushort_t*)alloc((size_t)MPAD * HC * 2); // packed fp16 h
    f16*   xh      = (f16*)alloc((size_t)MPAD * F_IN * 2);
    f16*   act     = (f16*)alloc((size_t)MPAD * HC * 2);
    f16*   w1t     = (f16*)alloc((size_t)HC * F_IN * 2);      // [256][128]
    f16*   w2t     = (f16*)alloc((size_t)HC * HC * 2);        // [256][256]

    hipMemsetAsync(d_ws, 0, zero_bytes, stream);

    // fused prep: edge hist (rank-recording) + fp16 conversions
    int prep_n = EP + XN4 + NW;
    prep_kernel<<<(prep_n + 255) / 256, 256, 0, stream>>>(
        ei + NE, x, W1, W2, deg, rank, xh, w1t, w2t);
    scan_p1<<<49, 256, 0, stream>>>(deg, partials);
    scan_p3<<<49, 256, 0, stream>>>(deg, partials, offs);
    edge_fill<<<(EP + 255) / 256, 256, 0, stream>>>(ei, ei + NE, offs, rank, csr);

    dim3 gg((NN + 127) / 128, HC / 128);
    int nb8 = (NN + 7) / 8;    // 2 nodes/wave * 4 waves/block

    // layer 1 (fp16 GEMM + fused alpha/packed-fp16-h epilogue)
    gemm_gat<<<gg, 256, 0, stream>>>(xh, w1t, a1s, a1d, hf2, asrc, adst, NN, F_IN);
    gat_agg<1><<<nb8, 256, 0, stream>>>(hf2, asrc, adst, offs, csr, batch, b1, act, nullptr);
    // layer 2 (aggregation fuses the mean-pool: atomics into pool)
    gemm_gat<<<gg, 256, 0, stream>>>(act, w2t, a2s, a2d, hf2, asrc, adst, NN, HC);
    gat_agg<0><<<nb8, 256, 0, stream>>>(hf2, asrc, adst, offs, csr, batch, b2, nullptr, pool);
    // readout (cnt via binary search; b2 folded in)
    fc_kernel<<<(NG * NOUT + 255) / 256, 256, 0, stream>>>(pool, batch, b2, fc_w, fc_b, out);
}

// Round 7
// 369.416 us; speedup vs baseline: 1.0286x; 1.0286x over previous
//
#include <hip/hip_runtime.h>
#include <hip/hip_bf16.h>
#include <cstddef>
#include <cstdint>

// Problem constants (from reference)
#define NN 50000
#define MPAD 50048      // 391 tiles * 128
#define F_IN 128
#define NH 4
#define NC 64
#define NE 800000
#define NG 128
#define NOUT 8
#define HC 256          // NH*NC
#define EP (NE + NN)    // edges + self loops
#define NREP 16         // pool replicas (atomic-contention spreading)

typedef unsigned short ushort_t;
typedef _Float16 f16;
typedef __attribute__((ext_vector_type(2))) _Float16 f16x2;
typedef __attribute__((ext_vector_type(8))) _Float16 f16x8;
typedef __attribute__((ext_vector_type(4))) float f32x4;

// ---------------------------------------------------------------------------
// helpers
// ---------------------------------------------------------------------------
__device__ __forceinline__ float lrelu02(float x) { return x > 0.0f ? x : 0.2f * x; }
__device__ __forceinline__ float elu1(float x)    { return x > 0.0f ? x : expm1f(x); }

__device__ __forceinline__ ushort_t f2h_bits(float f) {
    f16 h = (f16)f;
    union { f16 h; ushort_t u; } cv; cv.h = h;
    return cv.u;
}
__device__ __forceinline__ uint32_t pack2h(float a, float b) {
    union { f16 h[2]; uint32_t u; } cv;
    cv.h[0] = (f16)a; cv.h[1] = (f16)b;
    return cv.u;
}
__device__ __forceinline__ f16x2 as_h2(uint32_t q) {
    union { uint32_t u; f16x2 h; } cv; cv.u = q;
    return cv.h;
}
__device__ __forceinline__ void h2_unpack(uint32_t q, float& lo, float& hi) {
    union { uint32_t u; f16 h[2]; } cv; cv.u = q;
    lo = (float)cv.h[0];
    hi = (float)cv.h[1];
}

// v_dot2_f32_f16: acc += a.h0*b.h0 + a.h1*b.h1 (f32 accumulate, full rate).
__device__ __forceinline__ float fdot2f(f16x2 a, f16x2 b, float c) {
#if __has_builtin(__builtin_amdgcn_fdot2)
    return __builtin_amdgcn_fdot2(a, b, c, false);
#else
    float d;
    asm("v_dot2_f32_f16 %0, %1, %2, %3" : "=v"(d) : "v"(a), "v"(b), "v"(c));
    return d;
#endif
}
__device__ __forceinline__ uint32_t permb(uint32_t a, uint32_t b, uint32_t s) {
    return __builtin_amdgcn_perm(a, b, s);
}
// v_perm selectors: bytes 0-3 = src1(b), bytes 4-7 = src0(a).
// SEL_E -> (a.h0, b.h0) ; SEL_O -> (a.h1, b.h1)
#define SEL_E 0x01000504u
#define SEL_O 0x03020706u

// async global -> LDS, 16B per lane; lds dest = wave-uniform base + lane*16
__device__ __forceinline__ void gld16(const void* g, void* l) {
    __builtin_amdgcn_global_load_lds(
        (const __attribute__((address_space(1))) unsigned int*)g,
        (__attribute__((address_space(3))) unsigned int*)l, 16, 0, 0);
}

// ---------------------------------------------------------------------------
// fused prep: edge histogram (rank-recording) + x->fp16 + W->fp16^T
// atomicAdd's RETURN VALUE is the edge's rank within its dst bucket —
// stored to rank[] so edge_fill needs NO second atomic pass.
// ---------------------------------------------------------------------------
#define XN4 (NN * F_IN / 4)
#define NW (F_IN * HC + HC * HC)
__global__ void prep_kernel(const int* __restrict__ edst,
                            const float* __restrict__ x,
                            const float* __restrict__ W1,
                            const float* __restrict__ W2,
                            int* __restrict__ deg,
                            int* __restrict__ rank,
                            f16* __restrict__ xh,
                            f16* __restrict__ w1t, f16* __restrict__ w2t) {
    int idx = blockIdx.x * blockDim.x + threadIdx.x;
    if (idx < EP) {
        int d = (idx < NE) ? edst[idx] : (idx - NE);
        rank[idx] = atomicAdd(&deg[d], 1);
        return;
    }
    idx -= EP;
    if (idx < XN4) {
        float4 v = ((const float4*)x)[idx];
        f16 o[4] = {(f16)v.x, (f16)v.y, (f16)v.z, (f16)v.w};
        *(uint2*)(xh + idx * 4) = *(const uint2*)o;
        return;
    }
    idx -= XN4;
    const int n1 = F_IN * HC;
    if (idx < n1) {
        int k = idx / HC, n = idx % HC;
        w1t[n * F_IN + k] = (f16)W1[idx];
    } else if (idx < NW) {
        int i2 = idx - n1;
        int k = i2 / HC, n = i2 % HC;
        w2t[n * HC + k] = (f16)W2[i2];
    }
}

// ---------------------------------------------------------------------------
// CSR build: exclusive scan + fill (src ids, dst-sorted)
// ---------------------------------------------------------------------------
__global__ __launch_bounds__(256) void scan_p1(const int* __restrict__ deg,
                                               int* __restrict__ partials) {
    __shared__ int lds[256];
    int b = blockIdx.x, t = threadIdx.x;
    int i0 = b * 1024 + t * 4;
    int s = 0;
#pragma unroll
    for (int j = 0; j < 4; j++) { int i = i0 + j; if (i < NN) s += deg[i]; }
    lds[t] = s;
    __syncthreads();
    for (int o = 128; o; o >>= 1) { if (t < o) lds[t] += lds[t + o]; __syncthreads(); }
    if (t == 0) partials[b] = lds[0];
}

__global__ __launch_bounds__(256) void scan_p3(const int* __restrict__ deg,
                                               const int* __restrict__ partials,
                                               int* __restrict__ offs) {
    __shared__ int lds[256];
    __shared__ int base_s;
    int b = blockIdx.x, t = threadIdx.x;
    if (t == 0) {
        int s = 0;
        for (int i = 0; i < b; i++) s += partials[i];
        base_s = s;
        if (b == 0) offs[0] = 0;
    }
    int i0 = b * 1024 + t * 4;
    int v[4]; int s = 0;
#pragma unroll
    for (int j = 0; j < 4; j++) { int i = i0 + j; v[j] = (i < NN) ? deg[i] : 0; s += v[j]; }
    lds[t] = s;
    __syncthreads();
    for (int o = 1; o < 256; o <<= 1) {
        int x = (t >= o) ? lds[t - o] : 0;
        __syncthreads();
        lds[t] += x;
        __syncthreads();
    }
    int run = base_s + (lds[t] - s);
#pragma unroll
    for (int j = 0; j < 4; j++) { run += v[j]; int i = i0 + j; if (i < NN) offs[i + 1] = run; }
}

// no atomics — rank precomputed in prep. Pure read + scatter.
__global__ void edge_fill(const int* __restrict__ esrc, const int* __restrict__ edst,
                          const int* __restrict__ offs, const int* __restrict__ rank,
                          int* __restrict__ csr) {
    int e = blockIdx.x * blockDim.x + threadIdx.x;
    if (e >= EP) return;
    int s, d;
    if (e < NE) { s = esrc[e]; d = edst[e]; } else { s = d = e - NE; }
    csr[offs[d] + rank[e]] = s;
}

// ---------------------------------------------------------------------------
// fp16 MFMA GEMM, fused GAT epilogue (R10 shape, BK=32).
// hf2 dword layout [node][by*64+c]: dword = (hi: head 2by+1, lo: head 2by)
// packed fp16 for channel c (contiguous 256B/row per block).
// ---------------------------------------------------------------------------
__global__ __launch_bounds__(256, 3) void gemm_gat(
        const f16* __restrict__ A, const f16* __restrict__ BT,
        const float* __restrict__ a_s, const float* __restrict__ a_d,
        ushort_t* __restrict__ hf2, float* __restrict__ asrc,
        float* __restrict__ adst, int M, int K) {
    __shared__ alignas(16) char smem[33792];   // staging 16KB / repack 33.8KB
    f16* lA = (f16*)smem;            // [128 rows][32 k]
    f16* lB = (f16*)smem + 4096;     // [128 rows][32 k]

    int t = threadIdx.x;
    int wave = t >> 6, lane = t & 63;
    int wm = wave >> 1, wn = wave & 1;
    int quad = lane >> 4, l15 = lane & 15;
    int tileM = blockIdx.x * 128;
    int by = blockIdx.y;

    f32x4 acc[4][4];
#pragma unroll
    for (int f = 0; f < 4; f++)
#pragma unroll
        for (int g = 0; g < 4; g++) acc[f][g] = (f32x4){0.f, 0.f, 0.f, 0.f};

    for (int k0 = 0; k0 < K; k0 += 32) {
        __syncthreads();
#pragma unroll
        for (int i = 0; i < 2; i++) {
            int c = wave * 2 + i;
            int row = c * 16 + (lane >> 2);
            int kk = k0 + (lane & 3) * 8;
            gld16(A + (size_t)(tileM + row) * K + kk, &lA[c * 512]);
            gld16(BT + (size_t)(by * 128 + row) * K + kk, &lB[c * 512]);
        }
        __syncthreads();

        f16x8 ah[4], bh[4];
#pragma unroll
        for (int f = 0; f < 4; f++)
            ah[f] = *(const f16x8*)&lA[(wm * 64 + f * 16 + l15) * 32 + quad * 8];
#pragma unroll
        for (int g = 0; g < 4; g++)
            bh[g] = *(const f16x8*)&lB[(wn * 64 + g * 16 + l15) * 32 + quad * 8];
#pragma unroll
        for (int f = 0; f < 4; f++)
#pragma unroll
            for (int g = 0; g < 4; g++)
                acc[f][g] = __builtin_amdgcn_mfma_f32_16x16x32_f16(ah[f], bh[g], acc[f][g], 0, 0, 0);
    }

    // ---- epilogue 1: per-head attention dots (this wave's 64 cols = 1 head)
    int head = (by << 1) | wn;
    float as_v[4], ad_v[4];
#pragma unroll
    for (int g = 0; g < 4; g++) {
        as_v[g] = a_s[head * 64 + g * 16 + l15];
        ad_v[g] = a_d[head * 64 + g * 16 + l15];
    }
#pragma unroll
    for (int f = 0; f < 4; f++) {
#pragma unroll
        for (int r = 0; r < 4; r++) {
            float ps = acc[f][0][r] * as_v[0] + acc[f][1][r] * as_v[1]
                     + acc[f][2][r] * as_v[2] + acc[f][3][r] * as_v[3];
            float pd = acc[f][0][r] * ad_v[0] + acc[f][1][r] * ad_v[1]
                     + acc[f][2][r] * ad_v[2] + acc[f][3][r] * ad_v[3];
#pragma unroll
            for (int o = 1; o < 16; o <<= 1) {
                ps += __shfl_xor(ps, o);
                pd += __shfl_xor(pd, o);
            }
            int row = tileM + wm * 64 + f * 16 + quad * 4 + r;
            if (l15 == 0 && row < M) {
                asrc[row * 4 + head] = ps;
                adst[row * 4 + head] = pd;
            }
        }
    }

    // ---- epilogue 2: packed fp16 tile via padded LDS repack.
    __syncthreads();   // K-loop staging LDS dead
    ushort_t* lC2u = (ushort_t*)smem;
    const uint32_t* lC2d = (const uint32_t*)smem;
#pragma unroll
    for (int f = 0; f < 4; f++)
#pragma unroll
        for (int g = 0; g < 4; g++)
#pragma unroll
            for (int r = 0; r < 4; r++)
                lC2u[(wm * 64 + f * 16 + quad * 4 + r) * 132 + (g * 16 + l15) * 2 + wn] =
                    f2h_bits(acc[f][g][r]);
    __syncthreads();
    uint32_t* hb2 = (uint32_t*)hf2;
#pragma unroll
    for (int it = 0; it < 32; it++) {
        int row = wave * 32 + it;
        uint32_t v = lC2d[row * 66 + lane];
        hb2[(size_t)(tileM + row) * 128 + by * 64 + lane] = v;
    }
}

// ---------------------------------------------------------------------------
// Full-wave-per-node fallback (rare: any node in the wave's pair with deg>32).
// CONCAT=0 ending: atomics into the REPLICA-adjusted pool base (of).
// ---------------------------------------------------------------------------
template <int CONCAT>
__device__ void gat_node_fullwave(const ushort_t* __restrict__ hf2,
                                  const float* __restrict__ asrc,
                                  const float* __restrict__ adst,
                                  const int* __restrict__ offs,
                                  const int* __restrict__ csr,
                                  const int* __restrict__ gb,
                                  const float* __restrict__ bias,
                                  f16* __restrict__ oh,
                                  float* __restrict__ of,
                                  int node, int lane, uint2* lwF) {
    int start = offs[node];
    int deg = offs[node + 1] - start;
    float4 ad = *(const float4*)(adst + node * 4);

    float w0, w1, w2, w3;
    float m0, m1, m2, m3, i0, i1, i2, i3;
    int msrc = 0;

    if (deg <= 64) {
        float t0 = -1e30f, t1 = -1e30f, t2 = -1e30f, t3 = -1e30f;
        if (lane < deg) {
            int sidx = csr[start + lane];
            float4 as = *(const float4*)(asrc + sidx * 4);
            t0 = lrelu02(as.x + ad.x);
            t1 = lrelu02(as.y + ad.y);
            t2 = lrelu02(as.z + ad.z);
            t3 = lrelu02(as.w + ad.w);
            msrc = sidx;
        }
        m0 = t0; m1 = t1; m2 = t2; m3 = t3;
#pragma unroll
        for (int o = 1; o < 64; o <<= 1) {
            m0 = fmaxf(m0, __shfl_xor(m0, o));
            m1 = fmaxf(m1, __shfl_xor(m1, o));
            m2 = fmaxf(m2, __shfl_xor(m2, o));
            m3 = fmaxf(m3, __shfl_xor(m3, o));
        }
        w0 = __expf(t0 - m0);
        w1 = __expf(t1 - m1);
        w2 = __expf(t2 - m2);
        w3 = __expf(t3 - m3);
        float s0 = w0, s1 = w1, s2 = w2, s3 = w3;
#pragma unroll
        for (int o = 1; o < 64; o <<= 1) {
            s0 += __shfl_xor(s0, o);
            s1 += __shfl_xor(s1, o);
            s2 += __shfl_xor(s2, o);
            s3 += __shfl_xor(s3, o);
        }
        i0 = 1.0f / (s0 + 1e-16f);
        i1 = 1.0f / (s1 + 1e-16f);
        i2 = 1.0f / (s2 + 1e-16f);
        i3 = 1.0f / (s3 + 1e-16f);
        w0 *= i0; w1 *= i1; w2 *= i2; w3 *= i3;
    } else {
        m0 = m1 = m2 = m3 = -1e30f;
        float s0 = 0.f, s1 = 0.f, s2 = 0.f, s3 = 0.f;
        float e0 = 0.f, e1 = 0.f, e2 = 0.f, e3 = 0.f;
        for (int j = lane; j < deg; j += 64) {
            int sidx = csr[start + j];
            float4 as = *(const float4*)(asrc + sidx * 4);
            float t0 = lrelu02(as.x + ad.x);
            float t1 = lrelu02(as.y + ad.y);
            float t2 = lrelu02(as.z + ad.z);
            float t3 = lrelu02(as.w + ad.w);
            if (j == lane) { e0 = t0; e1 = t1; e2 = t2; e3 = t3; msrc = sidx; }
            float nm;
            nm = fmaxf(m0, t0); s0 = s0 * __expf(m0 - nm) + __expf(t0 - nm); m0 = nm;
            nm = fmaxf(m1, t1); s1 = s1 * __expf(m1 - nm) + __expf(t1 - nm); m1 = nm;
            nm = fmaxf(m2, t2); s2 = s2 * __expf(m2 - nm) + __expf(t2 - nm); m2 = nm;
            nm = fmaxf(m3, t3); s3 = s3 * __expf(m3 - nm) + __expf(t3 - nm); m3 = nm;
        }
        for (int o = 32; o; o >>= 1) {
            float om, os, nm;
            om = __shfl_xor(m0, o); os = __shfl_xor(s0, o);
            nm = fmaxf(m0, om); s0 = s0 * __expf(m0 - nm) + os * __expf(om - nm); m0 = nm;
            om = __shfl_xor(m1, o); os = __shfl_xor(s1, o);
            nm = fmaxf(m1, om); s1 = s1 * __expf(m1 - nm) + os * __expf(om - nm); m1 = nm;
            om = __shfl_xor(m2, o); os = __shfl_xor(s2, o);
            nm = fmaxf(m2, om); s2 = s2 * __expf(m2 - nm) + os * __expf(om - nm); m2 = nm;
            om = __shfl_xor(m3, o); os = __shfl_xor(s3, o);
            nm = fmaxf(m3, om); s3 = s3 * __expf(m3 - nm) + os * __expf(om - nm); m3 = nm;
        }
        i0 = 1.0f / (s0 + 1e-16f);
        i1 = 1.0f / (s1 + 1e-16f);
        i2 = 1.0f / (s2 + 1e-16f);
        i3 = 1.0f / (s3 + 1e-16f);
        w0 = __expf(e0 - m0) * i0;
        w1 = __expf(e1 - m1) * i1;
        w2 = __expf(e2 - m2) * i2;
        w3 = __expf(e3 - m3) * i3;
    }

    lwF[lane] = (uint2){pack2h(w0, w1), pack2h(w2, w3)};

    int hp = lane >> 5;
    const uint32_t* lwu = (const uint32_t*)lwF;
    float aE0 = 0.f, aO0 = 0.f, aE1 = 0.f, aO1 = 0.f;
    float c0a = 0.f, c0b = 0.f, c1a = 0.f, c1b = 0.f;
    const uint32_t* hb = (const uint32_t*)hf2 + lane * 2;
    int jmax = deg < 64 ? deg : 64;

    int j = 0;
    if (CONCAT) {
        for (; j + 4 <= jmax; j += 4) {
            int s0 = __builtin_amdgcn_readlane(msrc, j);
            int s1 = __builtin_amdgcn_readlane(msrc, j + 1);
            int s2 = __builtin_amdgcn_readlane(msrc, j + 2);
            int s3 = __builtin_amdgcn_readlane(msrc, j + 3);
            uint2 q0 = *(const uint2*)(hb + (size_t)s0 * 128);
            uint2 q1 = *(const uint2*)(hb + (size_t)s1 * 128);
            uint2 q2 = *(const uint2*)(hb + (size_t)s2 * 128);
            uint2 q3 = *(const uint2*)(hb + (size_t)s3 * 128);
            uint32_t wA = lwu[(j + 0) * 2 + hp];
            uint32_t wB = lwu[(j + 1) * 2 + hp];
            uint32_t wC = lwu[(j + 2) * 2 + hp];
            uint32_t wD = lwu[(j + 3) * 2 + hp];
            uint32_t weAB = permb(wA, wB, SEL_E), woAB = permb(wA, wB, SEL_O);
            uint32_t weCD = permb(wC, wD, SEL_E), woCD = permb(wC, wD, SEL_O);
            uint32_t xeAB = permb(q0.x, q1.x, SEL_E), xoAB = permb(q0.x, q1.x, SEL_O);
            uint32_t yeAB = permb(q0.y, q1.y, SEL_E), yoAB = permb(q0.y, q1.y, SEL_O);
            uint32_t xeCD = permb(q2.x, q3.x, SEL_E), xoCD = permb(q2.x, q3.x, SEL_O);
            uint32_t yeCD = permb(q2.y, q3.y, SEL_E), yoCD = permb(q2.y, q3.y, SEL_O);
            aE0 = fdot2f(as_h2(xeAB), as_h2(weAB), aE0);
            aO0 = fdot2f(as_h2(xoAB), as_h2(woAB), aO0);
            aE1 = fdot2f(as_h2(yeAB), as_h2(weAB), aE1);
            aO1 = fdot2f(as_h2(yoAB), as_h2(woAB), aO1);
            aE0 = fdot2f(as_h2(xeCD), as_h2(weCD), aE0);
            aO0 = fdot2f(as_h2(xoCD), as_h2(woCD), aO0);
            aE1 = fdot2f(as_h2(yeCD), as_h2(weCD), aE1);
            aO1 = fdot2f(as_h2(yoCD), as_h2(woCD), aO1);
        }
        for (; j < jmax; j++) {
            int sidx = __builtin_amdgcn_readlane(msrc, j);
            f16x2 wh = as_h2(lwu[j * 2 + hp]);
            uint2 q = *(const uint2*)(hb + (size_t)sidx * 128);
            f16x2 qx = as_h2(q.x), qy = as_h2(q.y);
            aE0 += (float)qx[0] * (float)wh[0];
            aO0 += (float)qx[1] * (float)wh[1];
            aE1 += (float)qy[0] * (float)wh[0];
            aO1 += (float)qy[1] * (float)wh[1];
        }
    } else {
        for (; j + 4 <= jmax; j += 4) {
            int s0 = __builtin_amdgcn_readlane(msrc, j);
            int s1 = __builtin_amdgcn_readlane(msrc, j + 1);
            int s2 = __builtin_amdgcn_readlane(msrc, j + 2);
            int s3 = __builtin_amdgcn_readlane(msrc, j + 3);
            uint2 q0 = *(const uint2*)(hb + (size_t)s0 * 128);
            uint2 q1 = *(const uint2*)(hb + (size_t)s1 * 128);
            uint2 q2 = *(const uint2*)(hb + (size_t)s2 * 128);
            uint2 q3 = *(const uint2*)(hb + (size_t)s3 * 128);
            f16x2 w0v = as_h2(lwu[(j + 0) * 2 + hp]);
            f16x2 w1v = as_h2(lwu[(j + 1) * 2 + hp]);
            f16x2 w2v = as_h2(lwu[(j + 2) * 2 + hp]);
            f16x2 w3v = as_h2(lwu[(j + 3) * 2 + hp]);
            c0a = fdot2f(as_h2(q0.x), w0v, c0a);
            c1a = fdot2f(as_h2(q0.y), w0v, c1a);
            c0b = fdot2f(as_h2(q1.x), w1v, c0b);
            c1b = fdot2f(as_h2(q1.y), w1v, c1b);
            c0a = fdot2f(as_h2(q2.x), w2v, c0a);
            c1a = fdot2f(as_h2(q2.y), w2v, c1a);
            c0b = fdot2f(as_h2(q3.x), w3v, c0b);
            c1b = fdot2f(as_h2(q3.y), w3v, c1b);
        }
        for (; j < jmax; j++) {
            int sidx = __builtin_amdgcn_readlane(msrc, j);
            f16x2 wh = as_h2(lwu[j * 2 + hp]);
            uint2 q = *(const uint2*)(hb + (size_t)sidx * 128);
            c0a = fdot2f(as_h2(q.x), wh, c0a);
            c1a = fdot2f(as_h2(q.y), wh, c1a);
        }
    }
    for (int jj = 64; jj < deg; jj++) {
        int sidx = csr[start + jj];
        float4 as = *(const float4*)(asrc + sidx * 4);
        float u0 = __expf(lrelu02(as.x + ad.x) - m0) * i0;
        float u1 = __expf(lrelu02(as.y + ad.y) - m1) * i1;
        float u2 = __expf(lrelu02(as.z + ad.z) - m2) * i2;
        float u3 = __expf(lrelu02(as.w + ad.w) - m3) * i3;
        float ue = hp ? u2 : u0;
        float uo = hp ? u3 : u1;
        uint2 q = *(const uint2*)(hb + (size_t)sidx * 128);
        float xl, xh2, yl, yh;
        h2_unpack(q.x, xl, xh2);
        h2_unpack(q.y, yl, yh);
        if (CONCAT) {
            aE0 += ue * xl;
            aO0 += uo * xh2;
            aE1 += ue * yl;
            aO1 += uo * yh;
        } else {
            c0a += ue * xl + uo * xh2;
            c1a += ue * yl + uo * yh;
        }
    }

    int c0 = (lane & 31) * 2;
    int he = hp * 2, ho = hp * 2 + 1;
    if (CONCAT) {
        size_t base = (size_t)node * HC;
        float vE0 = elu1(aE0 + bias[he * 64 + c0]);
        float vE1 = elu1(aE1 + bias[he * 64 + c0 + 1]);
        float vO0 = elu1(aO0 + bias[ho * 64 + c0]);
        float vO1 = elu1(aO1 + bias[ho * 64 + c0 + 1]);
        f16 pe[2] = {(f16)vE0, (f16)vE1};
        f16 po[2] = {(f16)vO0, (f16)vO1};
        *(uint32_t*)(oh + base + he * 64 + c0) = *(const uint32_t*)pe;
        *(uint32_t*)(oh + base + ho * 64 + c0) = *(const uint32_t*)po;
    } else {
        float s0 = c0a + c0b;
        float s1 = c1a + c1b;
        s0 += __shfl_xor(s0, 32);
        s1 += __shfl_xor(s1, 32);
        if (hp == 0) {
            int g = gb[node];
            atomicAdd(of + g * 64 + c0, 0.25f * s0);
            atomicAdd(of + g * 64 + c0 + 1, 0.25f * s1);
        }
    }
}

// ---------------------------------------------------------------------------
// GAT aggregation R19: two nodes/wave, double-buffered pipeline (R17) +
// fused mean-pool with 16-REPLICA atomic spreading. R18 post-mortem: direct
// pool atomics serialized (sorted batch -> all resident waves hit the same
// graph's 16 cache lines; agg<0> 69->124us). Fix: pool[NREP][NG][64],
// replica = blockIdx.x & (NREP-1) — consecutive blocks (same graph) go to
// different replicas; ~3 blocks per (g,rep) => no contention. fc sums reps.
// ---------------------------------------------------------------------------
template <int CONCAT>
__global__ __launch_bounds__(256, 4) void gat_agg(const ushort_t* __restrict__ hf2,
                                                  const float* __restrict__ asrc,
                                                  const float* __restrict__ adst,
                                                  const int* __restrict__ offs,
                                                  const int* __restrict__ csr,
                                                  const int* __restrict__ gb,
                                                  const float* __restrict__ bias,
                                                  f16* __restrict__ oh,
                                                  float* __restrict__ of) {
    __shared__ uint4 lw4[4][64];   // [wave][grp*32 + j] = {src, w01, src, w23}
    int wave = threadIdx.x >> 6, lane = threadIdx.x & 63;
    int grp = lane >> 5, l31 = lane & 31;
    int hp = (lane >> 4) & 1;      // head pair within group
    int nbase = blockIdx.x * 8 + wave * 2;   // NN % 8 == 0: always in range
    int node = nbase + grp;
    int start = offs[node];
    int deg = offs[node + 1] - start;

    // replica-adjusted pool base (CONCAT=0 only; harmless otherwise)
    float* ofr = of + (size_t)(blockIdx.x & (NREP - 1)) * NG * 64;

    if (!__all(deg <= 32)) {
        // rare fallback: full wave per node, sequentially
        uint2* lwF = (uint2*)&lw4[wave][0];
        gat_node_fullwave<CONCAT>(hf2, asrc, adst, offs, csr, gb, bias, oh, ofr,
                                  nbase, lane, lwF);
        gat_node_fullwave<CONCAT>(hf2, asrc, adst, offs, csr, gb, bias, oh, ofr,
                                  nbase + 1, lane, lwF);
        return;
    }

    // ---------- prologue: csr read, then EARLY batch-0/1 row loads ----------
    const uint4* hq = (const uint4*)hf2;   // hf2 row = 32 uint4
    int msrc = 0;
    bool act = l31 < deg;
    if (act) msrc = csr[start + l31];

    int b0 = grp * 32;
    int i0 = __shfl(msrc, b0 + 0);
    int i1 = __shfl(msrc, b0 + 1);
    int i2 = __shfl(msrc, b0 + 2);
    int i3 = __shfl(msrc, b0 + 3);
    int i4 = __shfl(msrc, b0 + 4);
    int i5 = __shfl(msrc, b0 + 5);
    int i6 = __shfl(msrc, b0 + 6);
    int i7 = __shfl(msrc, b0 + 7);
    uint4 q0 = hq[(uint32_t)i0 * 32u + l31];
    uint4 q1 = hq[(uint32_t)i1 * 32u + l31];
    uint4 q2 = hq[(uint32_t)i2 * 32u + l31];
    uint4 q3 = hq[(uint32_t)i3 * 32u + l31];
    uint4 r0 = hq[(uint32_t)i4 * 32u + l31];
    uint4 r1 = hq[(uint32_t)i5 * 32u + l31];
    uint4 r2 = hq[(uint32_t)i6 * 32u + l31];
    uint4 r3 = hq[(uint32_t)i7 * 32u + l31];

    // ---------- softmax over the 32-lane group (deg <= 32) ----------
    float4 ad = *(const float4*)(adst + (size_t)node * 4);
    float t0 = -1e30f, t1 = -1e30f, t2 = -1e30f, t3 = -1e30f;
    if (act) {
        float4 as = *(const float4*)(asrc + (size_t)msrc * 4);
        t0 = lrelu02(as.x + ad.x);
        t1 = lrelu02(as.y + ad.y);
        t2 = lrelu02(as.z + ad.z);
        t3 = lrelu02(as.w + ad.w);
    }
    float m0 = t0, m1 = t1, m2 = t2, m3 = t3;
#pragma unroll
    for (int o = 1; o < 32; o <<= 1) {
        m0 = fmaxf(m0, __shfl_xor(m0, o));
        m1 = fmaxf(m1, __shfl_xor(m1, o));
        m2 = fmaxf(m2, __shfl_xor(m2, o));
        m3 = fmaxf(m3, __shfl_xor(m3, o));
    }
    float w0 = __expf(t0 - m0);
    float w1 = __expf(t1 - m1);
    float w2 = __expf(t2 - m2);
    float w3 = __expf(t3 - m3);
    float s0 = w0, s1 = w1, s2 = w2, s3 = w3;
#pragma unroll
    for (int o = 1; o < 32; o <<= 1) {
        s0 += __shfl_xor(s0, o);
        s1 += __shfl_xor(s1, o);
        s2 += __shfl_xor(s2, o);
        s3 += __shfl_xor(s3, o);
    }
    w0 *= 1.0f / (s0 + 1e-16f);
    w1 *= 1.0f / (s1 + 1e-16f);
    w2 *= 1.0f / (s2 + 1e-16f);
    w3 *= 1.0f / (s3 + 1e-16f);

    // park per-edge entry (wave-private LDS; no barrier). pad lanes: w=0.
    lw4[wave][lane] = (uint4){(uint32_t)msrc, pack2h(w0, w1),
                              (uint32_t)msrc, pack2h(w2, w3)};

    const uint2* lwp = (const uint2*)&lw4[wave][grp * 32];  // entry j half hp
    int c0 = (l31 & 15) * 4;
    int deg4 = (deg + 3) & ~3;     // >= 4 (self-loop guarantees deg >= 1)

    // weights for batches 0 (q) and 1 (r), this lane's head pair
    uint32_t wy0 = lwp[0 * 2 + hp].y;
    uint32_t wy1 = lwp[1 * 2 + hp].y;
    uint32_t wy2 = lwp[2 * 2 + hp].y;
    uint32_t wy3 = lwp[3 * 2 + hp].y;
    uint32_t wz0 = lwp[4 * 2 + hp].y;
    uint32_t wz1 = lwp[5 * 2 + hp].y;
    uint32_t wz2 = lwp[6 * 2 + hp].y;
    uint32_t wz3 = lwp[7 * 2 + hp].y;

    if (CONCAT) {
        float aE0 = 0.f, aE1 = 0.f, aE2 = 0.f, aE3 = 0.f;
        float aO0 = 0.f, aO1 = 0.f, aO2 = 0.f, aO3 = 0.f;
#define CPAIR(A0, A1, W0, W1)                                                  \
        {                                                                      \
            uint32_t we = permb(W0, W1, SEL_E);                                \
            uint32_t wo = permb(W0, W1, SEL_O);                                \
            aE0 = fdot2f(as_h2(permb(A0.x, A1.x, SEL_E)), as_h2(we), aE0);     \
            aO0 = fdot2f(as_h2(permb(A0.x, A1.x, SEL_O)), as_h2(wo), aO0);     \
            aE1 = fdot2f(as_h2(permb(A0.y, A1.y, SEL_E)), as_h2(we), aE1);     \
            aO1 = fdot2f(as_h2(permb(A0.y, A1.y, SEL_O)), as_h2(wo), aO1);     \
            aE2 = fdot2f(as_h2(permb(A0.z, A1.z, SEL_E)), as_h2(we), aE2);     \
            aO2 = fdot2f(as_h2(permb(A0.z, A1.z, SEL_O)), as_h2(wo), aO2);     \
            aE3 = fdot2f(as_h2(permb(A0.w, A1.w, SEL_E)), as_h2(we), aE3);     \
            aO3 = fdot2f(as_h2(permb(A0.w, A1.w, SEL_O)), as_h2(wo), aO3);     \
        }
        int j = 0;
        for (;;) {
            // ---- compute q batch (edges j..j+3), prefetch j+8..j+11 -> q ----
            CPAIR(q0, q1, wy0, wy1)
            CPAIR(q2, q3, wy2, wy3)
            {
                int p = j + 8;
                if (p < deg4) {
                    uint2 n0 = lwp[(p + 0) * 2 + hp];
                    uint2 n1 = lwp[(p + 1) * 2 + hp];
                    uint2 n2 = lwp[(p + 2) * 2 + hp];
                    uint2 n3 = lwp[(p + 3) * 2 + hp];
                    wy0 = n0.y; wy1 = n1.y; wy2 = n2.y; wy3 = n3.y;
                    q0 = hq[n0.x * 32u + l31];
                    q1 = hq[n1.x * 32u + l31];
                    q2 = hq[n2.x * 32u + l31];
                    q3 = hq[n3.x * 32u + l31];
                }
            }
            j += 4;
            if (j >= deg4) break;
            // ---- compute r batch (edges j..j+3), prefetch j+8..j+11 -> r ----
            CPAIR(r0, r1, wz0, wz1)
            CPAIR(r2, r3, wz2, wz3)
            {
                int p = j + 8;
                if (p < deg4) {
                    uint2 n0 = lwp[(p + 0) * 2 + hp];
                    uint2 n1 = lwp[(p + 1) * 2 + hp];
                    uint2 n2 = lwp[(p + 2) * 2 + hp];
                    uint2 n3 = lwp[(p + 3) * 2 + hp];
                    wz0 = n0.y; wz1 = n1.y; wz2 = n2.y; wz3 = n3.y;
                    r0 = hq[n0.x * 32u + l31];
                    r1 = hq[n1.x * 32u + l31];
                    r2 = hq[n2.x * 32u + l31];
                    r3 = hq[n3.x * 32u + l31];
                }
            }
            j += 4;
            if (j >= deg4) break;
        }
#undef CPAIR
        // heads stay separate: lane writes 4 channels x (even,odd) heads
        int he = hp * 2, ho = hp * 2 + 1;
        size_t base = (size_t)node * HC;
        float4 bE = *(const float4*)(bias + he * 64 + c0);
        float4 bO = *(const float4*)(bias + ho * 64 + c0);
        f16 pe[4] = {(f16)elu1(aE0 + bE.x), (f16)elu1(aE1 + bE.y),
                     (f16)elu1(aE2 + bE.z), (f16)elu1(aE3 + bE.w)};
        f16 po[4] = {(f16)elu1(aO0 + bO.x), (f16)elu1(aO1 + bO.y),
                     (f16)elu1(aO2 + bO.z), (f16)elu1(aO3 + bO.w)};
        *(uint2*)(oh + base + he * 64 + c0) = *(const uint2*)pe;
        *(uint2*)(oh + base + ho * 64 + c0) = *(const uint2*)po;
    } else {
        float a0 = 0.f, a1 = 0.f, a2 = 0.f, a3 = 0.f;
        float b0f = 0.f, b1f = 0.f, b2f = 0.f, b3f = 0.f;
        int j = 0;
        for (;;) {
            // ---- compute q batch, prefetch j+8 -> q ----
            {
                f16x2 wvA = as_h2(wy0), wvB = as_h2(wy1);
                f16x2 wvC = as_h2(wy2), wvD = as_h2(wy3);
                a0 = fdot2f(as_h2(q0.x), wvA, a0);
                a1 = fdot2f(as_h2(q0.y), wvA, a1);
                a2 = fdot2f(as_h2(q0.z), wvA, a2);
                a3 = fdot2f(as_h2(q0.w), wvA, a3);
                b0f = fdot2f(as_h2(q1.x), wvB, b0f);
                b1f = fdot2f(as_h2(q1.y), wvB, b1f);
                b2f = fdot2f(as_h2(q1.z), wvB, b2f);
                b3f = fdot2f(as_h2(q1.w), wvB, b3f);
                a0 = fdot2f(as_h2(q2.x), wvC, a0);
                a1 = fdot2f(as_h2(q2.y), wvC, a1);
                a2 = fdot2f(as_h2(q2.z), wvC, a2);
                a3 = fdot2f(as_h2(q2.w), wvC, a3);
                b0f = fdot2f(as_h2(q3.x), wvD, b0f);
                b1f = fdot2f(as_h2(q3.y), wvD, b1f);
                b2f = fdot2f(as_h2(q3.z), wvD, b2f);
                b3f = fdot2f(as_h2(q3.w), wvD, b3f);
            }
            {
                int p = j + 8;
                if (p < deg4) {
                    uint2 n0 = lwp[(p + 0) * 2 + hp];
                    uint2 n1 = lwp[(p + 1) * 2 + hp];
                    uint2 n2 = lwp[(p + 2) * 2 + hp];
                    uint2 n3 = lwp[(p + 3) * 2 + hp];
                    wy0 = n0.y; wy1 = n1.y; wy2 = n2.y; wy3 = n3.y;
                    q0 = hq[n0.x * 32u + l31];
                    q1 = hq[n1.x * 32u + l31];
                    q2 = hq[n2.x * 32u + l31];
                    q3 = hq[n3.x * 32u + l31];
                }
            }
            j += 4;
            if (j >= deg4) break;
            // ---- compute r batch, prefetch j+8 -> r ----
            {
                f16x2 wvA = as_h2(wz0), wvB = as_h2(wz1);
                f16x2 wvC = as_h2(wz2), wvD = as_h2(wz3);
                a0 = fdot2f(as_h2(r0.x), wvA, a0);
                a1 = fdot2f(as_h2(r0.y), wvA, a1);
                a2 = fdot2f(as_h2(r0.z), wvA, a2);
                a3 = fdot2f(as_h2(r0.w), wvA, a3);
                b0f = fdot2f(as_h2(r1.x), wvB, b0f);
                b1f = fdot2f(as_h2(r1.y), wvB, b1f);
                b2f = fdot2f(as_h2(r1.z), wvB, b2f);
                b3f = fdot2f(as_h2(r1.w), wvB, b3f);
                a0 = fdot2f(as_h2(r2.x), wvC, a0);
                a1 = fdot2f(as_h2(r2.y), wvC, a1);
                a2 = fdot2f(as_h2(r2.z), wvC, a2);
                a3 = fdot2f(as_h2(r2.w), wvC, a3);
                b0f = fdot2f(as_h2(r3.x), wvD, b0f);
                b1f = fdot2f(as_h2(r3.y), wvD, b1f);
                b2f = fdot2f(as_h2(r3.z), wvD, b2f);
                b3f = fdot2f(as_h2(r3.w), wvD, b3f);
            }
            {
                int p = j + 8;
                if (p < deg4) {
                    uint2 n0 = lwp[(p + 0) * 2 + hp];
                    uint2 n1 = lwp[(p + 1) * 2 + hp];
                    uint2 n2 = lwp[(p + 2) * 2 + hp];
                    uint2 n3 = lwp[(p + 3) * 2 + hp];
                    wz0 = n0.y; wz1 = n1.y; wz2 = n2.y; wz3 = n3.y;
                    r0 = hq[n0.x * 32u + l31];
                    r1 = hq[n1.x * 32u + l31];
                    r2 = hq[n2.x * 32u + l31];
                    r3 = hq[n3.x * 32u + l31];
                }
            }
            j += 4;
            if (j >= deg4) break;
        }
        // head-pair sum is in each dot2; add the other hp via shfl_xor(16)
        float u0 = a0 + b0f, u1 = a1 + b1f, u2 = a2 + b2f, u3 = a3 + b3f;
        u0 += __shfl_xor(u0, 16);
        u1 += __shfl_xor(u1, 16);
        u2 += __shfl_xor(u2, 16);
        u3 += __shfl_xor(u3, 16);
        // ---- fused mean-pool: atomics into replica pool (no hot lines) ----
        float o0 = 0.25f * u0, o1 = 0.25f * u1, o2 = 0.25f * u2, o3 = 0.25f * u3;
        float p0 = __shfl_xor(o0, 32);
        float p1 = __shfl_xor(o1, 32);
        float p2 = __shfl_xor(o2, 32);
        float p3 = __shfl_xor(o3, 32);
        int g = gb[node];
        int gO = __shfl_xor(g, 32);
        if (hp == 0) {
            float* pb = ofr + g * 64 + c0;
            if (g == gO) {
                if (grp == 0) {   // one group carries both nodes' sums
                    atomicAdd(pb + 0, o0 + p0);
                    atomicAdd(pb + 1, o1 + p1);
                    atomicAdd(pb + 2, o2 + p2);
                    atomicAdd(pb + 3, o3 + p3);
                }
            } else {
                atomicAdd(pb + 0, o0);
                atomicAdd(pb + 1, o1);
                atomicAdd(pb + 2, o2);
                atomicAdd(pb + 3, o3);
            }
        }
    }
}

// ---------------------------------------------------------------------------
// fc: sums the NREP pool replicas; cnt via binary search over sorted batch;
// bias b2 folded in: pooled_c = (sum_r pool[r][g][c])/cnt + b2[c].
// ---------------------------------------------------------------------------
__global__ void fc_kernel(const float* __restrict__ pool,
                          const int* __restrict__ batch,
                          const float* __restrict__ b2,
                          const float* __restrict__ fc_w, const float* __restrict__ fc_b,
                          float* __restrict__ out) {
    int idx = blockIdx.x * blockDim.x + threadIdx.x;
    if (idx >= NG * NOUT) return;
    int g = idx >> 3, o = idx & 7;
    int lo = 0, hi = NN;
    while (lo < hi) { int mid = (lo + hi) >> 1; if (batch[mid] < g) lo = mid + 1; else hi = mid; }
    int lo2 = lo, hi2 = NN;
    while (lo2 < hi2) { int mid = (lo2 + hi2) >> 1; if (batch[mid] < g + 1) lo2 = mid + 1; else hi2 = mid; }
    float inv = 1.0f / fmaxf((float)(lo2 - lo), 1.0f);
    float s = 0.f;
#pragma unroll
    for (int c = 0; c < 64; c++) {
        float v = 0.f;
#pragma unroll
        for (int r = 0; r < NREP; r++) v += pool[((size_t)r * NG + g) * 64 + c];
        s += (v * inv + b2[c]) * fc_w[c * 8 + o];
    }
    out[idx] = s + fc_b[o];
}

// ---------------------------------------------------------------------------
extern "C" void kernel_launch(void* const* d_in, const int* in_sizes, int n_in,
                              void* d_out, int out_size, void* d_ws, size_t ws_size,
                              hipStream_t stream) {
    const float* x    = (const float*)d_in[0];
    const int*   ei   = (const int*)d_in[1];   // [2, E]
    const int*   batch= (const int*)d_in[2];
    const float* W1   = (const float*)d_in[3];
    const float* a1s  = (const float*)d_in[4];
    const float* a1d  = (const float*)d_in[5];
    const float* b1   = (const float*)d_in[6];
    const float* W2   = (const float*)d_in[7];
    const float* a2s  = (const float*)d_in[8];
    const float* a2d  = (const float*)d_in[9];
    const float* b2   = (const float*)d_in[10];
    const float* fc_w = (const float*)d_in[11];
    const float* fc_b = (const float*)d_in[12];
    float* out = (float*)d_out;

    char* p = (char*)d_ws;
    auto alloc = [&](size_t bytes) -> char* {
        char* r = p; p += (bytes + 255) & ~(size_t)255; return r;
    };
    int*   deg     = (int*)alloc((size_t)NN * 4);
    float* pool    = (float*)alloc((size_t)NREP * NG * 64 * 4);
    size_t zero_bytes = (size_t)(p - (char*)d_ws);
    int*   offs    = (int*)alloc((size_t)(NN + 1) * 4);
    int*   partials= (int*)alloc(64 * 4);
    int*   csr     = (int*)alloc((size_t)EP * 4);
    int*   rank    = (int*)alloc((size_t)EP * 4);
    float* asrc    = (float*)alloc((size_t)NN * 4 * 4);
    float* adst    = (float*)alloc((size_t)NN * 4 * 4);
    ushort_t* hf2  = (ushort_t*)alloc((size_t)MPAD * HC * 2); // packed fp16 h
    f16*   xh      = (f16*)alloc((size_t)MPAD * F_IN * 2);
    f16*   act     = (f16*)alloc((size_t)MPAD * HC * 2);
    f16*   w1t     = (f16*)alloc((size_t)HC * F_IN * 2);      // [256][128]
    f16*   w2t     = (f16*)alloc((size_t)HC * HC * 2);        // [256][256]

    hipMemsetAsync(d_ws, 0, zero_bytes, stream);

    // fused prep: edge hist (rank-recording) + fp16 conversions
    int prep_n = EP + XN4 + NW;
    prep_kernel<<<(prep_n + 255) / 256, 256, 0, stream>>>(
        ei + NE, x, W1, W2, deg, rank, xh, w1t, w2t);
    scan_p1<<<49, 256, 0, stream>>>(deg, partials);
    scan_p3<<<49, 256, 0, stream>>>(deg, partials, offs);
    edge_fill<<<(EP + 255) / 256, 256, 0, stream>>>(ei, ei + NE, offs, rank, csr);

    dim3 gg((NN + 127) / 128, HC / 128);
    int nb8 = (NN + 7) / 8;    // 2 nodes/wave * 4 waves/block

    // layer 1 (fp16 GEMM + fused alpha/packed-fp16-h epilogue)
    gemm_gat<<<gg, 256, 0, stream>>>(xh, w1t, a1s, a1d, hf2, asrc, adst, NN, F_IN);
    gat_agg<1><<<nb8, 256, 0, stream>>>(hf2, asrc, adst, offs, csr, batch, b1, act, nullptr);
    // layer 2 (aggregation fuses the mean-pool via replica atomics)
    gemm_gat<<<gg, 256, 0, stream>>>(act, w2t, a2s, a2d, hf2, asrc, adst, NN, HC);
    gat_agg<0><<<nb8, 256, 0, stream>>>(hf2, asrc, adst, offs, csr, batch, b2, nullptr, pool);
    // readout (replica sum + cnt binary search + b2 fold)
    fc_kernel<<<(NG * NOUT + 255) / 256, 256, 0, stream>>>(pool, batch, b2, fc_w, fc_b, out);
}

// Round 8
// 346.082 us; speedup vs baseline: 1.0980x; 1.0674x over previous
//
#include <hip/hip_runtime.h>
#include <hip/hip_bf16.h>
#include <cstddef>
#include <cstdint>

// Problem constants (from reference)
#define NN 50000
#define MPAD 50048      // 391 tiles * 128
#define F_IN 128
#define NH 4
#define NC 64
#define NE 800000
#define NG 128
#define NOUT 8
#define HC 256          // NH*NC
#define EP (NE + NN)    // edges + self loops
#define NREP 16         // pool replicas (atomic-contention spreading)

typedef unsigned short ushort_t;
typedef _Float16 f16;
typedef __attribute__((ext_vector_type(2))) _Float16 f16x2;
typedef __attribute__((ext_vector_type(8))) _Float16 f16x8;
typedef __attribute__((ext_vector_type(4))) float f32x4;

// ---------------------------------------------------------------------------
// helpers
// ---------------------------------------------------------------------------
__device__ __forceinline__ float lrelu02(float x) { return x > 0.0f ? x : 0.2f * x; }
__device__ __forceinline__ float elu1(float x)    { return x > 0.0f ? x : expm1f(x); }

__device__ __forceinline__ ushort_t f2h_bits(float f) {
    f16 h = (f16)f;
    union { f16 h; ushort_t u; } cv; cv.h = h;
    return cv.u;
}
__device__ __forceinline__ uint32_t pack2h(float a, float b) {
    union { f16 h[2]; uint32_t u; } cv;
    cv.h[0] = (f16)a; cv.h[1] = (f16)b;
    return cv.u;
}
__device__ __forceinline__ f16x2 as_h2(uint32_t q) {
    union { uint32_t u; f16x2 h; } cv; cv.u = q;
    return cv.h;
}
__device__ __forceinline__ void h2_unpack(uint32_t q, float& lo, float& hi) {
    union { uint32_t u; f16 h[2]; } cv; cv.u = q;
    lo = (float)cv.h[0];
    hi = (float)cv.h[1];
}

// v_dot2_f32_f16: acc += a.h0*b.h0 + a.h1*b.h1 (f32 accumulate, full rate).
__device__ __forceinline__ float fdot2f(f16x2 a, f16x2 b, float c) {
#if __has_builtin(__builtin_amdgcn_fdot2)
    return __builtin_amdgcn_fdot2(a, b, c, false);
#else
    float d;
    asm("v_dot2_f32_f16 %0, %1, %2, %3" : "=v"(d) : "v"(a), "v"(b), "v"(c));
    return d;
#endif
}
__device__ __forceinline__ uint32_t permb(uint32_t a, uint32_t b, uint32_t s) {
    return __builtin_amdgcn_perm(a, b, s);
}
// v_perm selectors: bytes 0-3 = src1(b), bytes 4-7 = src0(a).
// SEL_E -> (a.h0, b.h0) ; SEL_O -> (a.h1, b.h1)
#define SEL_E 0x01000504u
#define SEL_O 0x03020706u

// async global -> LDS, 16B per lane; lds dest = wave-uniform base + lane*16
__device__ __forceinline__ void gld16(const void* g, void* l) {
    __builtin_amdgcn_global_load_lds(
        (const __attribute__((address_space(1))) unsigned int*)g,
        (__attribute__((address_space(3))) unsigned int*)l, 16, 0, 0);
}

// ---------------------------------------------------------------------------
// fused prep: edge histogram (rank-recording) + x->fp16 + W->fp16^T
// atomicAdd's RETURN VALUE is the edge's rank within its dst bucket —
// stored to rank[] so edge_fill needs NO second atomic pass.
// ---------------------------------------------------------------------------
#define XN4 (NN * F_IN / 4)
#define NW (F_IN * HC + HC * HC)
__global__ void prep_kernel(const int* __restrict__ edst,
                            const float* __restrict__ x,
                            const float* __restrict__ W1,
                            const float* __restrict__ W2,
                            int* __restrict__ deg,
                            int* __restrict__ rank,
                            f16* __restrict__ xh,
                            f16* __restrict__ w1t, f16* __restrict__ w2t) {
    int idx = blockIdx.x * blockDim.x + threadIdx.x;
    if (idx < EP) {
        int d = (idx < NE) ? edst[idx] : (idx - NE);
        rank[idx] = atomicAdd(&deg[d], 1);
        return;
    }
    idx -= EP;
    if (idx < XN4) {
        float4 v = ((const float4*)x)[idx];
        f16 o[4] = {(f16)v.x, (f16)v.y, (f16)v.z, (f16)v.w};
        *(uint2*)(xh + idx * 4) = *(const uint2*)o;
        return;
    }
    idx -= XN4;
    const int n1 = F_IN * HC;
    if (idx < n1) {
        int k = idx / HC, n = idx % HC;
        w1t[n * F_IN + k] = (f16)W1[idx];
    } else if (idx < NW) {
        int i2 = idx - n1;
        int k = i2 / HC, n = i2 % HC;
        w2t[n * HC + k] = (f16)W2[i2];
    }
}

// ---------------------------------------------------------------------------
// CSR build: exclusive scan + fill (src ids, dst-sorted)
// ---------------------------------------------------------------------------
__global__ __launch_bounds__(256) void scan_p1(const int* __restrict__ deg,
                                               int* __restrict__ partials) {
    __shared__ int lds[256];
    int b = blockIdx.x, t = threadIdx.x;
    int i0 = b * 1024 + t * 4;
    int s = 0;
#pragma unroll
    for (int j = 0; j < 4; j++) { int i = i0 + j; if (i < NN) s += deg[i]; }
    lds[t] = s;
    __syncthreads();
    for (int o = 128; o; o >>= 1) { if (t < o) lds[t] += lds[t + o]; __syncthreads(); }
    if (t == 0) partials[b] = lds[0];
}

__global__ __launch_bounds__(256) void scan_p3(const int* __restrict__ deg,
                                               const int* __restrict__ partials,
                                               int* __restrict__ offs) {
    __shared__ int lds[256];
    __shared__ int base_s;
    int b = blockIdx.x, t = threadIdx.x;
    if (t == 0) {
        int s = 0;
        for (int i = 0; i < b; i++) s += partials[i];
        base_s = s;
        if (b == 0) offs[0] = 0;
    }
    int i0 = b * 1024 + t * 4;
    int v[4]; int s = 0;
#pragma unroll
    for (int j = 0; j < 4; j++) { int i = i0 + j; v[j] = (i < NN) ? deg[i] : 0; s += v[j]; }
    lds[t] = s;
    __syncthreads();
    for (int o = 1; o < 256; o <<= 1) {
        int x = (t >= o) ? lds[t - o] : 0;
        __syncthreads();
        lds[t] += x;
        __syncthreads();
    }
    int run = base_s + (lds[t] - s);
#pragma unroll
    for (int j = 0; j < 4; j++) { run += v[j]; int i = i0 + j; if (i < NN) offs[i + 1] = run; }
}

// no atomics — rank precomputed in prep. Pure read + scatter.
__global__ void edge_fill(const int* __restrict__ esrc, const int* __restrict__ edst,
                          const int* __restrict__ offs, const int* __restrict__ rank,
                          int* __restrict__ csr) {
    int e = blockIdx.x * blockDim.x + threadIdx.x;
    if (e >= EP) return;
    int s, d;
    if (e < NE) { s = esrc[e]; d = edst[e]; } else { s = d = e - NE; }
    csr[offs[d] + rank[e]] = s;
}

// ---------------------------------------------------------------------------
// fp16 MFMA GEMM, fused GAT epilogue (R10 shape, BK=32).
// hf2 dword layout [node][by*64+c]: dword = (hi: head 2by+1, lo: head 2by)
// packed fp16 for channel c (contiguous 256B/row per block).
// ---------------------------------------------------------------------------
__global__ __launch_bounds__(256, 3) void gemm_gat(
        const f16* __restrict__ A, const f16* __restrict__ BT,
        const float* __restrict__ a_s, const float* __restrict__ a_d,
        ushort_t* __restrict__ hf2, float* __restrict__ asrc,
        float* __restrict__ adst, int M, int K) {
    __shared__ alignas(16) char smem[33792];   // staging 16KB / repack 33.8KB
    f16* lA = (f16*)smem;            // [128 rows][32 k]
    f16* lB = (f16*)smem + 4096;     // [128 rows][32 k]

    int t = threadIdx.x;
    int wave = t >> 6, lane = t & 63;
    int wm = wave >> 1, wn = wave & 1;
    int quad = lane >> 4, l15 = lane & 15;
    int tileM = blockIdx.x * 128;
    int by = blockIdx.y;

    f32x4 acc[4][4];
#pragma unroll
    for (int f = 0; f < 4; f++)
#pragma unroll
        for (int g = 0; g < 4; g++) acc[f][g] = (f32x4){0.f, 0.f, 0.f, 0.f};

    for (int k0 = 0; k0 < K; k0 += 32) {
        __syncthreads();
#pragma unroll
        for (int i = 0; i < 2; i++) {
            int c = wave * 2 + i;
            int row = c * 16 + (lane >> 2);
            int kk = k0 + (lane & 3) * 8;
            gld16(A + (size_t)(tileM + row) * K + kk, &lA[c * 512]);
            gld16(BT + (size_t)(by * 128 + row) * K + kk, &lB[c * 512]);
        }
        __syncthreads();

        f16x8 ah[4], bh[4];
#pragma unroll
        for (int f = 0; f < 4; f++)
            ah[f] = *(const f16x8*)&lA[(wm * 64 + f * 16 + l15) * 32 + quad * 8];
#pragma unroll
        for (int g = 0; g < 4; g++)
            bh[g] = *(const f16x8*)&lB[(wn * 64 + g * 16 + l15) * 32 + quad * 8];
#pragma unroll
        for (int f = 0; f < 4; f++)
#pragma unroll
            for (int g = 0; g < 4; g++)
                acc[f][g] = __builtin_amdgcn_mfma_f32_16x16x32_f16(ah[f], bh[g], acc[f][g], 0, 0, 0);
    }

    // ---- epilogue 1: per-head attention dots (this wave's 64 cols = 1 head)
    int head = (by << 1) | wn;
    float as_v[4], ad_v[4];
#pragma unroll
    for (int g = 0; g < 4; g++) {
        as_v[g] = a_s[head * 64 + g * 16 + l15];
        ad_v[g] = a_d[head * 64 + g * 16 + l15];
    }
#pragma unroll
    for (int f = 0; f < 4; f++) {
#pragma unroll
        for (int r = 0; r < 4; r++) {
            float ps = acc[f][0][r] * as_v[0] + acc[f][1][r] * as_v[1]
                     + acc[f][2][r] * as_v[2] + acc[f][3][r] * as_v[3];
            float pd = acc[f][0][r] * ad_v[0] + acc[f][1][r] * ad_v[1]
                     + acc[f][2][r] * ad_v[2] + acc[f][3][r] * ad_v[3];
#pragma unroll
            for (int o = 1; o < 16; o <<= 1) {
                ps += __shfl_xor(ps, o);
                pd += __shfl_xor(pd, o);
            }
            int row = tileM + wm * 64 + f * 16 + quad * 4 + r;
            if (l15 == 0 && row < M) {
                asrc[row * 4 + head] = ps;
                adst[row * 4 + head] = pd;
            }
        }
    }

    // ---- epilogue 2: packed fp16 tile via padded LDS repack.
    __syncthreads();   // K-loop staging LDS dead
    ushort_t* lC2u = (ushort_t*)smem;
    const uint32_t* lC2d = (const uint32_t*)smem;
#pragma unroll
    for (int f = 0; f < 4; f++)
#pragma unroll
        for (int g = 0; g < 4; g++)
#pragma unroll
            for (int r = 0; r < 4; r++)
                lC2u[(wm * 64 + f * 16 + quad * 4 + r) * 132 + (g * 16 + l15) * 2 + wn] =
                    f2h_bits(acc[f][g][r]);
    __syncthreads();
    uint32_t* hb2 = (uint32_t*)hf2;
#pragma unroll
    for (int it = 0; it < 32; it++) {
        int row = wave * 32 + it;
        uint32_t v = lC2d[row * 66 + lane];
        hb2[(size_t)(tileM + row) * 128 + by * 64 + lane] = v;
    }
}

// ---------------------------------------------------------------------------
// Full-wave-per-node fallback (rare: any node in the wave's pair with deg>32).
// CONCAT=0 ending: DIRECT atomics into the replica-adjusted pool base (of).
// ---------------------------------------------------------------------------
template <int CONCAT>
__device__ void gat_node_fullwave(const ushort_t* __restrict__ hf2,
                                  const float* __restrict__ asrc,
                                  const float* __restrict__ adst,
                                  const int* __restrict__ offs,
                                  const int* __restrict__ csr,
                                  const int* __restrict__ gb,
                                  const float* __restrict__ bias,
                                  f16* __restrict__ oh,
                                  float* __restrict__ of,
                                  int node, int lane, uint2* lwF) {
    int start = offs[node];
    int deg = offs[node + 1] - start;
    float4 ad = *(const float4*)(adst + node * 4);

    float w0, w1, w2, w3;
    float m0, m1, m2, m3, i0, i1, i2, i3;
    int msrc = 0;

    if (deg <= 64) {
        float t0 = -1e30f, t1 = -1e30f, t2 = -1e30f, t3 = -1e30f;
        if (lane < deg) {
            int sidx = csr[start + lane];
            float4 as = *(const float4*)(asrc + sidx * 4);
            t0 = lrelu02(as.x + ad.x);
            t1 = lrelu02(as.y + ad.y);
            t2 = lrelu02(as.z + ad.z);
            t3 = lrelu02(as.w + ad.w);
            msrc = sidx;
        }
        m0 = t0; m1 = t1; m2 = t2; m3 = t3;
#pragma unroll
        for (int o = 1; o < 64; o <<= 1) {
            m0 = fmaxf(m0, __shfl_xor(m0, o));
            m1 = fmaxf(m1, __shfl_xor(m1, o));
            m2 = fmaxf(m2, __shfl_xor(m2, o));
            m3 = fmaxf(m3, __shfl_xor(m3, o));
        }
        w0 = __expf(t0 - m0);
        w1 = __expf(t1 - m1);
        w2 = __expf(t2 - m2);
        w3 = __expf(t3 - m3);
        float s0 = w0, s1 = w1, s2 = w2, s3 = w3;
#pragma unroll
        for (int o = 1; o < 64; o <<= 1) {
            s0 += __shfl_xor(s0, o);
            s1 += __shfl_xor(s1, o);
            s2 += __shfl_xor(s2, o);
            s3 += __shfl_xor(s3, o);
        }
        i0 = 1.0f / (s0 + 1e-16f);
        i1 = 1.0f / (s1 + 1e-16f);
        i2 = 1.0f / (s2 + 1e-16f);
        i3 = 1.0f / (s3 + 1e-16f);
        w0 *= i0; w1 *= i1; w2 *= i2; w3 *= i3;
    } else {
        m0 = m1 = m2 = m3 = -1e30f;
        float s0 = 0.f, s1 = 0.f, s2 = 0.f, s3 = 0.f;
        float e0 = 0.f, e1 = 0.f, e2 = 0.f, e3 = 0.f;
        for (int j = lane; j < deg; j += 64) {
            int sidx = csr[start + j];
            float4 as = *(const float4*)(asrc + sidx * 4);
            float t0 = lrelu02(as.x + ad.x);
            float t1 = lrelu02(as.y + ad.y);
            float t2 = lrelu02(as.z + ad.z);
            float t3 = lrelu02(as.w + ad.w);
            if (j == lane) { e0 = t0; e1 = t1; e2 = t2; e3 = t3; msrc = sidx; }
            float nm;
            nm = fmaxf(m0, t0); s0 = s0 * __expf(m0 - nm) + __expf(t0 - nm); m0 = nm;
            nm = fmaxf(m1, t1); s1 = s1 * __expf(m1 - nm) + __expf(t1 - nm); m1 = nm;
            nm = fmaxf(m2, t2); s2 = s2 * __expf(m2 - nm) + __expf(t2 - nm); m2 = nm;
            nm = fmaxf(m3, t3); s3 = s3 * __expf(m3 - nm) + __expf(t3 - nm); m3 = nm;
        }
        for (int o = 32; o; o >>= 1) {
            float om, os, nm;
            om = __shfl_xor(m0, o); os = __shfl_xor(s0, o);
            nm = fmaxf(m0, om); s0 = s0 * __expf(m0 - nm) + os * __expf(om - nm); m0 = nm;
            om = __shfl_xor(m1, o); os = __shfl_xor(s1, o);
            nm = fmaxf(m1, om); s1 = s1 * __expf(m1 - nm) + os * __expf(om - nm); m1 = nm;
            om = __shfl_xor(m2, o); os = __shfl_xor(s2, o);
            nm = fmaxf(m2, om); s2 = s2 * __expf(m2 - nm) + os * __expf(om - nm); m2 = nm;
            om = __shfl_xor(m3, o); os = __shfl_xor(s3, o);
            nm = fmaxf(m3, om); s3 = s3 * __expf(m3 - nm) + os * __expf(om - nm); m3 = nm;
        }
        i0 = 1.0f / (s0 + 1e-16f);
        i1 = 1.0f / (s1 + 1e-16f);
        i2 = 1.0f / (s2 + 1e-16f);
        i3 = 1.0f / (s3 + 1e-16f);
        w0 = __expf(e0 - m0) * i0;
        w1 = __expf(e1 - m1) * i1;
        w2 = __expf(e2 - m2) * i2;
        w3 = __expf(e3 - m3) * i3;
    }

    lwF[lane] = (uint2){pack2h(w0, w1), pack2h(w2, w3)};

    int hp = lane >> 5;
    const uint32_t* lwu = (const uint32_t*)lwF;
    float aE0 = 0.f, aO0 = 0.f, aE1 = 0.f, aO1 = 0.f;
    float c0a = 0.f, c0b = 0.f, c1a = 0.f, c1b = 0.f;
    const uint32_t* hb = (const uint32_t*)hf2 + lane * 2;
    int jmax = deg < 64 ? deg : 64;

    int j = 0;
    if (CONCAT) {
        for (; j + 4 <= jmax; j += 4) {
            int s0 = __builtin_amdgcn_readlane(msrc, j);
            int s1 = __builtin_amdgcn_readlane(msrc, j + 1);
            int s2 = __builtin_amdgcn_readlane(msrc, j + 2);
            int s3 = __builtin_amdgcn_readlane(msrc, j + 3);
            uint2 q0 = *(const uint2*)(hb + (size_t)s0 * 128);
            uint2 q1 = *(const uint2*)(hb + (size_t)s1 * 128);
            uint2 q2 = *(const uint2*)(hb + (size_t)s2 * 128);
            uint2 q3 = *(const uint2*)(hb + (size_t)s3 * 128);
            uint32_t wA = lwu[(j + 0) * 2 + hp];
            uint32_t wB = lwu[(j + 1) * 2 + hp];
            uint32_t wC = lwu[(j + 2) * 2 + hp];
            uint32_t wD = lwu[(j + 3) * 2 + hp];
            uint32_t weAB = permb(wA, wB, SEL_E), woAB = permb(wA, wB, SEL_O);
            uint32_t weCD = permb(wC, wD, SEL_E), woCD = permb(wC, wD, SEL_O);
            uint32_t xeAB = permb(q0.x, q1.x, SEL_E), xoAB = permb(q0.x, q1.x, SEL_O);
            uint32_t yeAB = permb(q0.y, q1.y, SEL_E), yoAB = permb(q0.y, q1.y, SEL_O);
            uint32_t xeCD = permb(q2.x, q3.x, SEL_E), xoCD = permb(q2.x, q3.x, SEL_O);
            uint32_t yeCD = permb(q2.y, q3.y, SEL_E), yoCD = permb(q2.y, q3.y, SEL_O);
            aE0 = fdot2f(as_h2(xeAB), as_h2(weAB), aE0);
            aO0 = fdot2f(as_h2(xoAB), as_h2(woAB), aO0);
            aE1 = fdot2f(as_h2(yeAB), as_h2(weAB), aE1);
            aO1 = fdot2f(as_h2(yoAB), as_h2(woAB), aO1);
            aE0 = fdot2f(as_h2(xeCD), as_h2(weCD), aE0);
            aO0 = fdot2f(as_h2(xoCD), as_h2(woCD), aO0);
            aE1 = fdot2f(as_h2(yeCD), as_h2(weCD), aE1);
            aO1 = fdot2f(as_h2(yeCD), as_h2(woCD), aO1);
        }
        for (; j < jmax; j++) {
            int sidx = __builtin_amdgcn_readlane(msrc, j);
            f16x2 wh = as_h2(lwu[j * 2 + hp]);
            uint2 q = *(const uint2*)(hb + (size_t)sidx * 128);
            f16x2 qx = as_h2(q.x), qy = as_h2(q.y);
            aE0 += (float)qx[0] * (float)wh[0];
            aO0 += (float)qx[1] * (float)wh[1];
            aE1 += (float)qy[0] * (float)wh[0];
            aO1 += (float)qy[1] * (float)wh[1];
        }
    } else {
        for (; j + 4 <= jmax; j += 4) {
            int s0 = __builtin_amdgcn_readlane(msrc, j);
            int s1 = __builtin_amdgcn_readlane(msrc, j + 1);
            int s2 = __builtin_amdgcn_readlane(msrc, j + 2);
            int s3 = __builtin_amdgcn_readlane(msrc, j + 3);
            uint2 q0 = *(const uint2*)(hb + (size_t)s0 * 128);
            uint2 q1 = *(const uint2*)(hb + (size_t)s1 * 128);
            uint2 q2 = *(const uint2*)(hb + (size_t)s2 * 128);
            uint2 q3 = *(const uint2*)(hb + (size_t)s3 * 128);
            f16x2 w0v = as_h2(lwu[(j + 0) * 2 + hp]);
            f16x2 w1v = as_h2(lwu[(j + 1) * 2 + hp]);
            f16x2 w2v = as_h2(lwu[(j + 2) * 2 + hp]);
            f16x2 w3v = as_h2(lwu[(j + 3) * 2 + hp]);
            c0a = fdot2f(as_h2(q0.x), w0v, c0a);
            c1a = fdot2f(as_h2(q0.y), w0v, c1a);
            c0b = fdot2f(as_h2(q1.x), w1v, c0b);
            c1b = fdot2f(as_h2(q1.y), w1v, c1b);
            c0a = fdot2f(as_h2(q2.x), w2v, c0a);
            c1a = fdot2f(as_h2(q2.y), w2v, c1a);
            c0b = fdot2f(as_h2(q3.x), w3v, c0b);
            c1b = fdot2f(as_h2(q3.y), w3v, c1b);
        }
        for (; j < jmax; j++) {
            int sidx = __builtin_amdgcn_readlane(msrc, j);
            f16x2 wh = as_h2(lwu[j * 2 + hp]);
            uint2 q = *(const uint2*)(hb + (size_t)sidx * 128);
            c0a = fdot2f(as_h2(q.x), wh, c0a);
            c1a = fdot2f(as_h2(q.y), wh, c1a);
        }
    }
    for (int jj = 64; jj < deg; jj++) {
        int sidx = csr[start + jj];
        float4 as = *(const float4*)(asrc + sidx * 4);
        float u0 = __expf(lrelu02(as.x + ad.x) - m0) * i0;
        float u1 = __expf(lrelu02(as.y + ad.y) - m1) * i1;
        float u2 = __expf(lrelu02(as.z + ad.z) - m2) * i2;
        float u3 = __expf(lrelu02(as.w + ad.w) - m3) * i3;
        float ue = hp ? u2 : u0;
        float uo = hp ? u3 : u1;
        uint2 q = *(const uint2*)(hb + (size_t)sidx * 128);
        float xl, xh2, yl, yh;
        h2_unpack(q.x, xl, xh2);
        h2_unpack(q.y, yl, yh);
        if (CONCAT) {
            aE0 += ue * xl;
            aO0 += uo * xh2;
            aE1 += ue * yl;
            aO1 += uo * yh;
        } else {
            c0a += ue * xl + uo * xh2;
            c1a += ue * yl + uo * yh;
        }
    }

    int c0 = (lane & 31) * 2;
    int he = hp * 2, ho = hp * 2 + 1;
    if (CONCAT) {
        size_t base = (size_t)node * HC;
        float vE0 = elu1(aE0 + bias[he * 64 + c0]);
        float vE1 = elu1(aE1 + bias[he * 64 + c0 + 1]);
        float vO0 = elu1(aO0 + bias[ho * 64 + c0]);
        float vO1 = elu1(aO1 + bias[ho * 64 + c0 + 1]);
        f16 pe[2] = {(f16)vE0, (f16)vE1};
        f16 po[2] = {(f16)vO0, (f16)vO1};
        *(uint32_t*)(oh + base + he * 64 + c0) = *(const uint32_t*)pe;
        *(uint32_t*)(oh + base + ho * 64 + c0) = *(const uint32_t*)po;
    } else {
        float s0 = c0a + c0b;
        float s1 = c1a + c1b;
        s0 += __shfl_xor(s0, 32);
        s1 += __shfl_xor(s1, 32);
        if (hp == 0) {
            int g = gb[node];
            atomicAdd(of + g * 64 + c0, 0.25f * s0);
            atomicAdd(of + g * 64 + c0 + 1, 0.25f * s1);
        }
    }
}

// ---------------------------------------------------------------------------
// GAT aggregation R20: two nodes/wave, double-buffered pipeline (R17) +
// fused mean-pool with BLOCK-LEVEL LDS REDUCTION. R19 post-mortem: replicas
// spread addresses but not per-line totals (12.5K atomics/graph fixed);
// residual +26us = ~390 serial RMW/line. Only lever: atomic COUNT.
// This version: block-uniform vote (all 4 waves deg<=32) -> each wave
// ds_add_f32's its 64 channel values into part[slot][64] (block's 8 nodes
// span <=2 graphs; slot 0 = g_first, slot 1 = g_last) -> barrier -> ONE
// global atomic set (64 dwords) per block-graph. Global atomics 1.6M->0.4M.
// Mixed blocks / mid-graph lanes: direct atomics, no barriers crossed.
// ---------------------------------------------------------------------------
template <int CONCAT>
__global__ __launch_bounds__(256, 4) void gat_agg(const ushort_t* __restrict__ hf2,
                                                  const float* __restrict__ asrc,
                                                  const float* __restrict__ adst,
                                                  const int* __restrict__ offs,
                                                  const int* __restrict__ csr,
                                                  const int* __restrict__ gb,
                                                  const float* __restrict__ bias,
                                                  f16* __restrict__ oh,
                                                  float* __restrict__ of) {
    __shared__ uint4 lw4[4][64];   // [wave][grp*32 + j] = {src, w01, src, w23}
    __shared__ float part[2][64];  // CONCAT=0: block pool partials
    __shared__ int oks[4];         // CONCAT=0: per-wave fast-path vote
    int wave = threadIdx.x >> 6, lane = threadIdx.x & 63;
    int grp = lane >> 5, l31 = lane & 31;
    int hp = (lane >> 4) & 1;      // head pair within group
    int nbase = blockIdx.x * 8 + wave * 2;   // NN % 8 == 0: always in range
    int node = nbase + grp;
    int start = offs[node];
    int deg = offs[node + 1] - start;

    // replica-adjusted pool base (CONCAT=0 only; harmless otherwise)
    float* ofr = of + (size_t)(blockIdx.x & (NREP - 1)) * NG * 64;

    bool ok = __all(deg <= 32);
    bool useLds = false;
    int g_first = 0, g_last = 0;
    if (!CONCAT) {
        // block-uniform vote BEFORE any divergent return (barrier safety)
        if (threadIdx.x < 128) ((float*)part)[threadIdx.x] = 0.f;
        if (lane == 0) oks[wave] = ok ? 1 : 0;
        __syncthreads();
        useLds = oks[0] && oks[1] && oks[2] && oks[3];
        g_first = gb[blockIdx.x * 8];
        g_last  = gb[blockIdx.x * 8 + 7];
    }

    if (!ok) {
        // rare fallback: full wave per node, sequentially (direct atomics)
        uint2* lwF = (uint2*)&lw4[wave][0];
        gat_node_fullwave<CONCAT>(hf2, asrc, adst, offs, csr, gb, bias, oh, ofr,
                                  nbase, lane, lwF);
        gat_node_fullwave<CONCAT>(hf2, asrc, adst, offs, csr, gb, bias, oh, ofr,
                                  nbase + 1, lane, lwF);
        return;
    }

    // ---------- prologue: csr read, then EARLY batch-0/1 row loads ----------
    const uint4* hq = (const uint4*)hf2;   // hf2 row = 32 uint4
    int msrc = 0;
    bool act = l31 < deg;
    if (act) msrc = csr[start + l31];

    int b0 = grp * 32;
    int i0 = __shfl(msrc, b0 + 0);
    int i1 = __shfl(msrc, b0 + 1);
    int i2 = __shfl(msrc, b0 + 2);
    int i3 = __shfl(msrc, b0 + 3);
    int i4 = __shfl(msrc, b0 + 4);
    int i5 = __shfl(msrc, b0 + 5);
    int i6 = __shfl(msrc, b0 + 6);
    int i7 = __shfl(msrc, b0 + 7);
    uint4 q0 = hq[(uint32_t)i0 * 32u + l31];
    uint4 q1 = hq[(uint32_t)i1 * 32u + l31];
    uint4 q2 = hq[(uint32_t)i2 * 32u + l31];
    uint4 q3 = hq[(uint32_t)i3 * 32u + l31];
    uint4 r0 = hq[(uint32_t)i4 * 32u + l31];
    uint4 r1 = hq[(uint32_t)i5 * 32u + l31];
    uint4 r2 = hq[(uint32_t)i6 * 32u + l31];
    uint4 r3 = hq[(uint32_t)i7 * 32u + l31];

    // ---------- softmax over the 32-lane group (deg <= 32) ----------
    float4 ad = *(const float4*)(adst + (size_t)node * 4);
    float t0 = -1e30f, t1 = -1e30f, t2 = -1e30f, t3 = -1e30f;
    if (act) {
        float4 as = *(const float4*)(asrc + (size_t)msrc * 4);
        t0 = lrelu02(as.x + ad.x);
        t1 = lrelu02(as.y + ad.y);
        t2 = lrelu02(as.z + ad.z);
        t3 = lrelu02(as.w + ad.w);
    }
    float m0 = t0, m1 = t1, m2 = t2, m3 = t3;
#pragma unroll
    for (int o = 1; o < 32; o <<= 1) {
        m0 = fmaxf(m0, __shfl_xor(m0, o));
        m1 = fmaxf(m1, __shfl_xor(m1, o));
        m2 = fmaxf(m2, __shfl_xor(m2, o));
        m3 = fmaxf(m3, __shfl_xor(m3, o));
    }
    float w0 = __expf(t0 - m0);
    float w1 = __expf(t1 - m1);
    float w2 = __expf(t2 - m2);
    float w3 = __expf(t3 - m3);
    float s0 = w0, s1 = w1, s2 = w2, s3 = w3;
#pragma unroll
    for (int o = 1; o < 32; o <<= 1) {
        s0 += __shfl_xor(s0, o);
        s1 += __shfl_xor(s1, o);
        s2 += __shfl_xor(s2, o);
        s3 += __shfl_xor(s3, o);
    }
    w0 *= 1.0f / (s0 + 1e-16f);
    w1 *= 1.0f / (s1 + 1e-16f);
    w2 *= 1.0f / (s2 + 1e-16f);
    w3 *= 1.0f / (s3 + 1e-16f);

    // park per-edge entry (wave-private LDS; no barrier). pad lanes: w=0.
    lw4[wave][lane] = (uint4){(uint32_t)msrc, pack2h(w0, w1),
                              (uint32_t)msrc, pack2h(w2, w3)};

    const uint2* lwp = (const uint2*)&lw4[wave][grp * 32];  // entry j half hp
    int c0 = (l31 & 15) * 4;
    int deg4 = (deg + 3) & ~3;     // >= 4 (self-loop guarantees deg >= 1)

    // weights for batches 0 (q) and 1 (r), this lane's head pair
    uint32_t wy0 = lwp[0 * 2 + hp].y;
    uint32_t wy1 = lwp[1 * 2 + hp].y;
    uint32_t wy2 = lwp[2 * 2 + hp].y;
    uint32_t wy3 = lwp[3 * 2 + hp].y;
    uint32_t wz0 = lwp[4 * 2 + hp].y;
    uint32_t wz1 = lwp[5 * 2 + hp].y;
    uint32_t wz2 = lwp[6 * 2 + hp].y;
    uint32_t wz3 = lwp[7 * 2 + hp].y;

    if (CONCAT) {
        float aE0 = 0.f, aE1 = 0.f, aE2 = 0.f, aE3 = 0.f;
        float aO0 = 0.f, aO1 = 0.f, aO2 = 0.f, aO3 = 0.f;
#define CPAIR(A0, A1, W0, W1)                                                  \
        {                                                                      \
            uint32_t we = permb(W0, W1, SEL_E);                                \
            uint32_t wo = permb(W0, W1, SEL_O);                                \
            aE0 = fdot2f(as_h2(permb(A0.x, A1.x, SEL_E)), as_h2(we), aE0);     \
            aO0 = fdot2f(as_h2(permb(A0.x, A1.x, SEL_O)), as_h2(wo), aO0);     \
            aE1 = fdot2f(as_h2(permb(A0.y, A1.y, SEL_E)), as_h2(we), aE1);     \
            aO1 = fdot2f(as_h2(permb(A0.y, A1.y, SEL_O)), as_h2(wo), aO1);     \
            aE2 = fdot2f(as_h2(permb(A0.z, A1.z, SEL_E)), as_h2(we), aE2);     \
            aO2 = fdot2f(as_h2(permb(A0.z, A1.z, SEL_O)), as_h2(wo), aO2);     \
            aE3 = fdot2f(as_h2(permb(A0.w, A1.w, SEL_E)), as_h2(we), aE3);     \
            aO3 = fdot2f(as_h2(permb(A0.w, A1.w, SEL_O)), as_h2(wo), aO3);     \
        }
        int j = 0;
        for (;;) {
            // ---- compute q batch (edges j..j+3), prefetch j+8..j+11 -> q ----
            CPAIR(q0, q1, wy0, wy1)
            CPAIR(q2, q3, wy2, wy3)
            {
                int p = j + 8;
                if (p < deg4) {
                    uint2 n0 = lwp[(p + 0) * 2 + hp];
                    uint2 n1 = lwp[(p + 1) * 2 + hp];
                    uint2 n2 = lwp[(p + 2) * 2 + hp];
                    uint2 n3 = lwp[(p + 3) * 2 + hp];
                    wy0 = n0.y; wy1 = n1.y; wy2 = n2.y; wy3 = n3.y;
                    q0 = hq[n0.x * 32u + l31];
                    q1 = hq[n1.x * 32u + l31];
                    q2 = hq[n2.x * 32u + l31];
                    q3 = hq[n3.x * 32u + l31];
                }
            }
            j += 4;
            if (j >= deg4) break;
            // ---- compute r batch (edges j..j+3), prefetch j+8..j+11 -> r ----
            CPAIR(r0, r1, wz0, wz1)
            CPAIR(r2, r3, wz2, wz3)
            {
                int p = j + 8;
                if (p < deg4) {
                    uint2 n0 = lwp[(p + 0) * 2 + hp];
                    uint2 n1 = lwp[(p + 1) * 2 + hp];
                    uint2 n2 = lwp[(p + 2) * 2 + hp];
                    uint2 n3 = lwp[(p + 3) * 2 + hp];
                    wz0 = n0.y; wz1 = n1.y; wz2 = n2.y; wz3 = n3.y;
                    r0 = hq[n0.x * 32u + l31];
                    r1 = hq[n1.x * 32u + l31];
                    r2 = hq[n2.x * 32u + l31];
                    r3 = hq[n3.x * 32u + l31];
                }
            }
            j += 4;
            if (j >= deg4) break;
        }
#undef CPAIR
        // heads stay separate: lane writes 4 channels x (even,odd) heads
        int he = hp * 2, ho = hp * 2 + 1;
        size_t base = (size_t)node * HC;
        float4 bE = *(const float4*)(bias + he * 64 + c0);
        float4 bO = *(const float4*)(bias + ho * 64 + c0);
        f16 pe[4] = {(f16)elu1(aE0 + bE.x), (f16)elu1(aE1 + bE.y),
                     (f16)elu1(aE2 + bE.z), (f16)elu1(aE3 + bE.w)};
        f16 po[4] = {(f16)elu1(aO0 + bO.x), (f16)elu1(aO1 + bO.y),
                     (f16)elu1(aO2 + bO.z), (f16)elu1(aO3 + bO.w)};
        *(uint2*)(oh + base + he * 64 + c0) = *(const uint2*)pe;
        *(uint2*)(oh + base + ho * 64 + c0) = *(const uint2*)po;
    } else {
        float a0 = 0.f, a1 = 0.f, a2 = 0.f, a3 = 0.f;
        float b0f = 0.f, b1f = 0.f, b2f = 0.f, b3f = 0.f;
        int j = 0;
        for (;;) {
            // ---- compute q batch, prefetch j+8 -> q ----
            {
                f16x2 wvA = as_h2(wy0), wvB = as_h2(wy1);
                f16x2 wvC = as_h2(wy2), wvD = as_h2(wy3);
                a0 = fdot2f(as_h2(q0.x), wvA, a0);
                a1 = fdot2f(as_h2(q0.y), wvA, a1);
                a2 = fdot2f(as_h2(q0.z), wvA, a2);
                a3 = fdot2f(as_h2(q0.w), wvA, a3);
                b0f = fdot2f(as_h2(q1.x), wvB, b0f);
                b1f = fdot2f(as_h2(q1.y), wvB, b1f);
                b2f = fdot2f(as_h2(q1.z), wvB, b2f);
                b3f = fdot2f(as_h2(q1.w), wvB, b3f);
                a0 = fdot2f(as_h2(q2.x), wvC, a0);
                a1 = fdot2f(as_h2(q2.y), wvC, a1);
                a2 = fdot2f(as_h2(q2.z), wvC, a2);
                a3 = fdot2f(as_h2(q2.w), wvC, a3);
                b0f = fdot2f(as_h2(q3.x), wvD, b0f);
                b1f = fdot2f(as_h2(q3.y), wvD, b1f);
                b2f = fdot2f(as_h2(q3.z), wvD, b2f);
                b3f = fdot2f(as_h2(q3.w), wvD, b3f);
            }
            {
                int p = j + 8;
                if (p < deg4) {
                    uint2 n0 = lwp[(p + 0) * 2 + hp];
                    uint2 n1 = lwp[(p + 1) * 2 + hp];
                    uint2 n2 = lwp[(p + 2) * 2 + hp];
                    uint2 n3 = lwp[(p + 3) * 2 + hp];
                    wy0 = n0.y; wy1 = n1.y; wy2 = n2.y; wy3 = n3.y;
                    q0 = hq[n0.x * 32u + l31];
                    q1 = hq[n1.x * 32u + l31];
                    q2 = hq[n2.x * 32u + l31];
                    q3 = hq[n3.x * 32u + l31];
                }
            }
            j += 4;
            if (j >= deg4) break;
            // ---- compute r batch, prefetch j+8 -> r ----
            {
                f16x2 wvA = as_h2(wz0), wvB = as_h2(wz1);
                f16x2 wvC = as_h2(wz2), wvD = as_h2(wz3);
                a0 = fdot2f(as_h2(r0.x), wvA, a0);
                a1 = fdot2f(as_h2(r0.y), wvA, a1);
                a2 = fdot2f(as_h2(r0.z), wvA, a2);
                a3 = fdot2f(as_h2(r0.w), wvA, a3);
                b0f = fdot2f(as_h2(r1.x), wvB, b0f);
                b1f = fdot2f(as_h2(r1.y), wvB, b1f);
                b2f = fdot2f(as_h2(r1.z), wvB, b2f);
                b3f = fdot2f(as_h2(r1.w), wvB, b3f);
                a0 = fdot2f(as_h2(r2.x), wvC, a0);
                a1 = fdot2f(as_h2(r2.y), wvC, a1);
                a2 = fdot2f(as_h2(r2.z), wvC, a2);
                a3 = fdot2f(as_h2(r2.w), wvC, a3);
                b0f = fdot2f(as_h2(r3.x), wvD, b0f);
                b1f = fdot2f(as_h2(r3.y), wvD, b1f);
                b2f = fdot2f(as_h2(r3.z), wvD, b2f);
                b3f = fdot2f(as_h2(r3.w), wvD, b3f);
            }
            {
                int p = j + 8;
                if (p < deg4) {
                    uint2 n0 = lwp[(p + 0) * 2 + hp];
                    uint2 n1 = lwp[(p + 1) * 2 + hp];
                    uint2 n2 = lwp[(p + 2) * 2 + hp];
                    uint2 n3 = lwp[(p + 3) * 2 + hp];
                    wz0 = n0.y; wz1 = n1.y; wz2 = n2.y; wz3 = n3.y;
                    r0 = hq[n0.x * 32u + l31];
                    r1 = hq[n1.x * 32u + l31];
                    r2 = hq[n2.x * 32u + l31];
                    r3 = hq[n3.x * 32u + l31];
                }
            }
            j += 4;
            if (j >= deg4) break;
        }
        // head-pair sum is in each dot2; add the other hp via shfl_xor(16)
        float u0 = a0 + b0f, u1 = a1 + b1f, u2 = a2 + b2f, u3 = a3 + b3f;
        u0 += __shfl_xor(u0, 16);
        u1 += __shfl_xor(u1, 16);
        u2 += __shfl_xor(u2, 16);
        u3 += __shfl_xor(u3, 16);
        float o0 = 0.25f * u0, o1 = 0.25f * u1, o2 = 0.25f * u2, o3 = 0.25f * u3;
        int g = gb[node];
        if (hp == 0) {
            bool inLds = useLds && (g == g_first || g == g_last);
            if (inLds) {
                int slot = (g != g_first) ? 1 : 0;
                atomicAdd(&part[slot][c0 + 0], o0);
                atomicAdd(&part[slot][c0 + 1], o1);
                atomicAdd(&part[slot][c0 + 2], o2);
                atomicAdd(&part[slot][c0 + 3], o3);
            } else {
                float* pb = ofr + g * 64 + c0;
                atomicAdd(pb + 0, o0);
                atomicAdd(pb + 1, o1);
                atomicAdd(pb + 2, o2);
                atomicAdd(pb + 3, o3);
            }
        }
        if (useLds) {
            __syncthreads();   // block-uniform: all 4 waves on fast path
            int t = threadIdx.x;
            if (t < 64) {
                atomicAdd(ofr + g_first * 64 + t, part[0][t]);
            } else if (t < 128 && g_last != g_first) {
                atomicAdd(ofr + g_last * 64 + (t - 64), part[1][t - 64]);
            }
        }
    }
}

// ---------------------------------------------------------------------------
// fc: sums the NREP pool replicas; cnt via binary search over sorted batch;
// bias b2 folded in: pooled_c = (sum_r pool[r][g][c])/cnt + b2[c].
// ---------------------------------------------------------------------------
__global__ void fc_kernel(const float* __restrict__ pool,
                          const int* __restrict__ batch,
                          const float* __restrict__ b2,
                          const float* __restrict__ fc_w, const float* __restrict__ fc_b,
                          float* __restrict__ out) {
    int idx = blockIdx.x * blockDim.x + threadIdx.x;
    if (idx >= NG * NOUT) return;
    int g = idx >> 3, o = idx & 7;
    int lo = 0, hi = NN;
    while (lo < hi) { int mid = (lo + hi) >> 1; if (batch[mid] < g) lo = mid + 1; else hi = mid; }
    int lo2 = lo, hi2 = NN;
    while (lo2 < hi2) { int mid = (lo2 + hi2) >> 1; if (batch[mid] < g + 1) lo2 = mid + 1; else hi2 = mid; }
    float inv = 1.0f / fmaxf((float)(lo2 - lo), 1.0f);
    float s = 0.f;
#pragma unroll
    for (int c = 0; c < 64; c++) {
        float v = 0.f;
#pragma unroll
        for (int r = 0; r < NREP; r++) v += pool[((size_t)r * NG + g) * 64 + c];
        s += (v * inv + b2[c]) * fc_w[c * 8 + o];
    }
    out[idx] = s + fc_b[o];
}

// ---------------------------------------------------------------------------
extern "C" void kernel_launch(void* const* d_in, const int* in_sizes, int n_in,
                              void* d_out, int out_size, void* d_ws, size_t ws_size,
                              hipStream_t stream) {
    const float* x    = (const float*)d_in[0];
    const int*   ei   = (const int*)d_in[1];   // [2, E]
    const int*   batch= (const int*)d_in[2];
    const float* W1   = (const float*)d_in[3];
    const float* a1s  = (const float*)d_in[4];
    const float* a1d  = (const float*)d_in[5];
    const float* b1   = (const float*)d_in[6];
    const float* W2   = (const float*)d_in[7];
    const float* a2s  = (const float*)d_in[8];
    const float* a2d  = (const float*)d_in[9];
    const float* b2   = (const float*)d_in[10];
    const float* fc_w = (const float*)d_in[11];
    const float* fc_b = (const float*)d_in[12];
    float* out = (float*)d_out;

    char* p = (char*)d_ws;
    auto alloc = [&](size_t bytes) -> char* {
        char* r = p; p += (bytes + 255) & ~(size_t)255; return r;
    };
    int*   deg     = (int*)alloc((size_t)NN * 4);
    float* pool    = (float*)alloc((size_t)NREP * NG * 64 * 4);
    size_t zero_bytes = (size_t)(p - (char*)d_ws);
    int*   offs    = (int*)alloc((size_t)(NN + 1) * 4);
    int*   partials= (int*)alloc(64 * 4);
    int*   csr     = (int*)alloc((size_t)EP * 4);
    int*   rank    = (int*)alloc((size_t)EP * 4);
    float* asrc    = (float*)alloc((size_t)NN * 4 * 4);
    float* adst    = (float*)alloc((size_t)NN * 4 * 4);
    ushort_t* hf2  = (ushort_t*)alloc((size_t)MPAD * HC * 2); // packed fp16 h
    f16*   xh      = (f16*)alloc((size_t)MPAD * F_IN * 2);
    f16*   act     = (f16*)alloc((size_t)MPAD * HC * 2);
    f16*   w1t     = (f16*)alloc((size_t)HC * F_IN * 2);      // [256][128]
    f16*   w2t     = (f16*)alloc((size_t)HC * HC * 2);        // [256][256]

    hipMemsetAsync(d_ws, 0, zero_bytes, stream);

    // fused prep: edge hist (rank-recording) + fp16 conversions
    int prep_n = EP + XN4 + NW;
    prep_kernel<<<(prep_n + 255) / 256, 256, 0, stream>>>(
        ei + NE, x, W1, W2, deg, rank, xh, w1t, w2t);
    scan_p1<<<49, 256, 0, stream>>>(deg, partials);
    scan_p3<<<49, 256, 0, stream>>>(deg, partials, offs);
    edge_fill<<<(EP + 255) / 256, 256, 0, stream>>>(ei, ei + NE, offs, rank, csr);

    dim3 gg((NN + 127) / 128, HC / 128);
    int nb8 = (NN + 7) / 8;    // 2 nodes/wave * 4 waves/block

    // layer 1 (fp16 GEMM + fused alpha/packed-fp16-h epilogue)
    gemm_gat<<<gg, 256, 0, stream>>>(xh, w1t, a1s, a1d, hf2, asrc, adst, NN, F_IN);
    gat_agg<1><<<nb8, 256, 0, stream>>>(hf2, asrc, adst, offs, csr, batch, b1, act, nullptr);
    // layer 2 (aggregation fuses the mean-pool: LDS block reduce + replicas)
    gemm_gat<<<gg, 256, 0, stream>>>(act, w2t, a2s, a2d, hf2, asrc, adst, NN, HC);
    gat_agg<0><<<nb8, 256, 0, stream>>>(hf2, asrc, adst, offs, csr, batch, b2, nullptr, pool);
    // readout (replica sum + cnt binary search + b2 fold)
    fc_kernel<<<(NG * NOUT + 255) / 256, 256, 0, stream>>>(pool, batch, b2, fc_w, fc_b, out);
}

// Round 9
// 333.215 us; speedup vs baseline: 1.1404x; 1.0386x over previous
//
#include <hip/hip_runtime.h>
#include <hip/hip_bf16.h>
#include <cstddef>
#include <cstdint>

// Problem constants (from reference)
#define NN 50000
#define MPAD 50048      // 391 tiles * 128
#define F_IN 128
#define NH 4
#define NC 64
#define NE 800000
#define NG 128
#define NOUT 8
#define HC 256          // NH*NC
#define EP (NE + NN)    // edges + self loops
#define NREP 16         // pool replicas (atomic-contention spreading)

typedef unsigned short ushort_t;
typedef _Float16 f16;
typedef __attribute__((ext_vector_type(2))) _Float16 f16x2;
typedef __attribute__((ext_vector_type(8))) _Float16 f16x8;
typedef __attribute__((ext_vector_type(4))) float f32x4;

// ---------------------------------------------------------------------------
// helpers
// ---------------------------------------------------------------------------
__device__ __forceinline__ float lrelu02(float x) { return x > 0.0f ? x : 0.2f * x; }
__device__ __forceinline__ float elu1(float x)    { return x > 0.0f ? x : expm1f(x); }

__device__ __forceinline__ ushort_t f2h_bits(float f) {
    f16 h = (f16)f;
    union { f16 h; ushort_t u; } cv; cv.h = h;
    return cv.u;
}
__device__ __forceinline__ uint32_t pack2h(float a, float b) {
    union { f16 h[2]; uint32_t u; } cv;
    cv.h[0] = (f16)a; cv.h[1] = (f16)b;
    return cv.u;
}
__device__ __forceinline__ f16x2 as_h2(uint32_t q) {
    union { uint32_t u; f16x2 h; } cv; cv.u = q;
    return cv.h;
}
__device__ __forceinline__ void h2_unpack(uint32_t q, float& lo, float& hi) {
    union { uint32_t u; f16 h[2]; } cv; cv.u = q;
    lo = (float)cv.h[0];
    hi = (float)cv.h[1];
}

// v_dot2_f32_f16: acc += a.h0*b.h0 + a.h1*b.h1 (f32 accumulate, full rate).
__device__ __forceinline__ float fdot2f(f16x2 a, f16x2 b, float c) {
#if __has_builtin(__builtin_amdgcn_fdot2)
    return __builtin_amdgcn_fdot2(a, b, c, false);
#else
    float d;
    asm("v_dot2_f32_f16 %0, %1, %2, %3" : "=v"(d) : "v"(a), "v"(b), "v"(c));
    return d;
#endif
}
__device__ __forceinline__ uint32_t permb(uint32_t a, uint32_t b, uint32_t s) {
    return __builtin_amdgcn_perm(a, b, s);
}
// v_perm selectors: bytes 0-3 = src1(b), bytes 4-7 = src0(a).
// SEL_E -> (a.h0, b.h0) ; SEL_O -> (a.h1, b.h1)
#define SEL_E 0x01000504u
#define SEL_O 0x03020706u

// async global -> LDS, 16B per lane; lds dest = wave-uniform base + lane*16
__device__ __forceinline__ void gld16(const void* g, void* l) {
    __builtin_amdgcn_global_load_lds(
        (const __attribute__((address_space(1))) unsigned int*)g,
        (__attribute__((address_space(3))) unsigned int*)l, 16, 0, 0);
}

// ---------------------------------------------------------------------------
// fused prep: edge histogram (rank-recording) + x->fp16 + W->fp16^T
// atomicAdd's RETURN VALUE is the edge's rank within its dst bucket —
// stored to rank[] so the CSR fill needs NO second atomic pass.
// ---------------------------------------------------------------------------
#define XN4 (NN * F_IN / 4)
#define NW (F_IN * HC + HC * HC)
__global__ void prep_kernel(const int* __restrict__ edst,
                            const float* __restrict__ x,
                            const float* __restrict__ W1,
                            const float* __restrict__ W2,
                            int* __restrict__ deg,
                            int* __restrict__ rank,
                            f16* __restrict__ xh,
                            f16* __restrict__ w1t, f16* __restrict__ w2t) {
    int idx = blockIdx.x * blockDim.x + threadIdx.x;
    if (idx < EP) {
        int d = (idx < NE) ? edst[idx] : (idx - NE);
        rank[idx] = atomicAdd(&deg[d], 1);
        return;
    }
    idx -= EP;
    if (idx < XN4) {
        float4 v = ((const float4*)x)[idx];
        f16 o[4] = {(f16)v.x, (f16)v.y, (f16)v.z, (f16)v.w};
        *(uint2*)(xh + idx * 4) = *(const uint2*)o;
        return;
    }
    idx -= XN4;
    const int n1 = F_IN * HC;
    if (idx < n1) {
        int k = idx / HC, n = idx % HC;
        w1t[n * F_IN + k] = (f16)W1[idx];
    } else if (idx < NW) {
        int i2 = idx - n1;
        int k = i2 / HC, n = i2 % HC;
        w2t[n * HC + k] = (f16)W2[i2];
    }
}

// ---------------------------------------------------------------------------
// CSR build: exclusive scan (fill is fused into gemm1's tail blocks)
// ---------------------------------------------------------------------------
__global__ __launch_bounds__(256) void scan_p1(const int* __restrict__ deg,
                                               int* __restrict__ partials) {
    __shared__ int lds[256];
    int b = blockIdx.x, t = threadIdx.x;
    int i0 = b * 1024 + t * 4;
    int s = 0;
#pragma unroll
    for (int j = 0; j < 4; j++) { int i = i0 + j; if (i < NN) s += deg[i]; }
    lds[t] = s;
    __syncthreads();
    for (int o = 128; o; o >>= 1) { if (t < o) lds[t] += lds[t + o]; __syncthreads(); }
    if (t == 0) partials[b] = lds[0];
}

__global__ __launch_bounds__(256) void scan_p3(const int* __restrict__ deg,
                                               const int* __restrict__ partials,
                                               int* __restrict__ offs) {
    __shared__ int lds[256];
    __shared__ int base_s;
    int b = blockIdx.x, t = threadIdx.x;
    if (t == 0) {
        int s = 0;
        for (int i = 0; i < b; i++) s += partials[i];
        base_s = s;
        if (b == 0) offs[0] = 0;
    }
    int i0 = b * 1024 + t * 4;
    int v[4]; int s = 0;
#pragma unroll
    for (int j = 0; j < 4; j++) { int i = i0 + j; v[j] = (i < NN) ? deg[i] : 0; s += v[j]; }
    lds[t] = s;
    __syncthreads();
    for (int o = 1; o < 256; o <<= 1) {
        int x = (t >= o) ? lds[t - o] : 0;
        __syncthreads();
        lds[t] += x;
        __syncthreads();
    }
    int run = base_s + (lds[t] - s);
#pragma unroll
    for (int j = 0; j < 4; j++) { run += v[j]; int i = i0 + j; if (i < NN) offs[i + 1] = run; }
}

// ---------------------------------------------------------------------------
// fp16 MFMA GEMM, fused GAT epilogue. R21:
//  - BK=64: half the vmcnt(0)+barrier drains per K (K=128: 2 iters, 256: 4).
//  - LDS XOR swizzle (rule #21: linear gld16 dest + inverse-swizzled GLOBAL
//    source + swizzled ds_read): old [row][BK] tiles had fragment reads at
//    64B/128B row stride -> 8/16-way bank conflicts. Swizzle granule = 8 f16
//    (16B): stage column block (l&7)^(l>>3); read block (h*4+quad)^(l15&7).
//    Lanes now cover all 32 banks (2-way = free).
//  - edge_fill FUSED as tail blocks of the layer-1 grid (independent work
//    fills gemm's barrier-stall shadow; one launch fewer).
// hf2 dword layout [node][by*64+c]: dword = (hi: head 2by+1, lo: head 2by).
// ---------------------------------------------------------------------------
__global__ __launch_bounds__(256, 3) void gemm_gat(
        const f16* __restrict__ A, const f16* __restrict__ BT,
        const float* __restrict__ a_s, const float* __restrict__ a_d,
        ushort_t* __restrict__ hf2, float* __restrict__ asrc,
        float* __restrict__ adst, int M, int K, int gemmBlocks,
        const int* __restrict__ esrc, const int* __restrict__ edst,
        const int* __restrict__ offs, const int* __restrict__ rank,
        int* __restrict__ csr) {
    __shared__ alignas(16) char smem[33792];   // staging 32KB / repack 33.8KB

    int bid = blockIdx.x;
    if (bid >= gemmBlocks) {
        // ---- edge_fill tail: pure read + scatter (rank precomputed) ----
        int e = (bid - gemmBlocks) * 256 + threadIdx.x;
        if (e < EP) {
            int s, d;
            if (e < NE) { s = esrc[e]; d = edst[e]; } else { s = d = e - NE; }
            csr[offs[d] + rank[e]] = s;
        }
        return;
    }

    f16* lA = (f16*)smem;            // [128 rows][64 k] (column-swizzled)
    f16* lB = (f16*)smem + 8192;     // [128 rows][64 k]

    int t = threadIdx.x;
    int wave = t >> 6, lane = t & 63;
    int wm = wave >> 1, wn = wave & 1;
    int quad = lane >> 4, l15 = lane & 15;
    int tileM = (bid >> 1) * 128;    // by-pairs adjacent in dispatch order
    int by = bid & 1;

    f32x4 acc[4][4];
#pragma unroll
    for (int f = 0; f < 4; f++)
#pragma unroll
        for (int g = 0; g < 4; g++) acc[f][g] = (f32x4){0.f, 0.f, 0.f, 0.f};

    int swl = ((lane & 7) ^ (lane >> 3)) * 8;   // swizzled k-block for staging
    int rsw = l15 & 7;                          // row&7 for fragment reads

    for (int k0 = 0; k0 < K; k0 += 64) {
        __syncthreads();
#pragma unroll
        for (int i = 0; i < 4; i++) {
            int c = wave * 4 + i;              // 0..15, 8 rows per call
            int row = c * 8 + (lane >> 3);
            int kk = k0 + swl;
            gld16(A + (size_t)(tileM + row) * K + kk, &lA[c * 512]);
            gld16(BT + (size_t)(by * 128 + row) * K + kk, &lB[c * 512]);
        }
        __syncthreads();

#pragma unroll
        for (int h = 0; h < 2; h++) {
            f16x8 ah[4], bh[4];
#pragma unroll
            for (int f = 0; f < 4; f++)
                ah[f] = *(const f16x8*)&lA[(wm * 64 + f * 16 + l15) * 64 +
                                           (((h * 4 + quad) ^ rsw) * 8)];
#pragma unroll
            for (int g = 0; g < 4; g++)
                bh[g] = *(const f16x8*)&lB[(wn * 64 + g * 16 + l15) * 64 +
                                           (((h * 4 + quad) ^ rsw) * 8)];
#pragma unroll
            for (int f = 0; f < 4; f++)
#pragma unroll
                for (int g = 0; g < 4; g++)
                    acc[f][g] = __builtin_amdgcn_mfma_f32_16x16x32_f16(
                        ah[f], bh[g], acc[f][g], 0, 0, 0);
        }
    }

    // ---- epilogue 1: per-head attention dots (this wave's 64 cols = 1 head)
    int head = (by << 1) | wn;
    float as_v[4], ad_v[4];
#pragma unroll
    for (int g = 0; g < 4; g++) {
        as_v[g] = a_s[head * 64 + g * 16 + l15];
        ad_v[g] = a_d[head * 64 + g * 16 + l15];
    }
#pragma unroll
    for (int f = 0; f < 4; f++) {
#pragma unroll
        for (int r = 0; r < 4; r++) {
            float ps = acc[f][0][r] * as_v[0] + acc[f][1][r] * as_v[1]
                     + acc[f][2][r] * as_v[2] + acc[f][3][r] * as_v[3];
            float pd = acc[f][0][r] * ad_v[0] + acc[f][1][r] * ad_v[1]
                     + acc[f][2][r] * ad_v[2] + acc[f][3][r] * ad_v[3];
#pragma unroll
            for (int o = 1; o < 16; o <<= 1) {
                ps += __shfl_xor(ps, o);
                pd += __shfl_xor(pd, o);
            }
            int row = tileM + wm * 64 + f * 16 + quad * 4 + r;
            if (l15 == 0 && row < M) {
                asrc[row * 4 + head] = ps;
                adst[row * 4 + head] = pd;
            }
        }
    }

    // ---- epilogue 2: packed fp16 tile via padded LDS repack.
    __syncthreads();   // K-loop staging LDS dead
    ushort_t* lC2u = (ushort_t*)smem;
    const uint32_t* lC2d = (const uint32_t*)smem;
#pragma unroll
    for (int f = 0; f < 4; f++)
#pragma unroll
        for (int g = 0; g < 4; g++)
#pragma unroll
            for (int r = 0; r < 4; r++)
                lC2u[(wm * 64 + f * 16 + quad * 4 + r) * 132 + (g * 16 + l15) * 2 + wn] =
                    f2h_bits(acc[f][g][r]);
    __syncthreads();
    uint32_t* hb2 = (uint32_t*)hf2;
#pragma unroll
    for (int it = 0; it < 32; it++) {
        int row = wave * 32 + it;
        uint32_t v = lC2d[row * 66 + lane];
        hb2[(size_t)(tileM + row) * 128 + by * 64 + lane] = v;
    }
}

// ---------------------------------------------------------------------------
// Full-wave-per-node fallback (rare: any node in the wave's pair with deg>32).
// CONCAT=0 ending: DIRECT atomics into the replica-adjusted pool base (of).
// ---------------------------------------------------------------------------
template <int CONCAT>
__device__ void gat_node_fullwave(const ushort_t* __restrict__ hf2,
                                  const float* __restrict__ asrc,
                                  const float* __restrict__ adst,
                                  const int* __restrict__ offs,
                                  const int* __restrict__ csr,
                                  const int* __restrict__ gb,
                                  const float* __restrict__ bias,
                                  f16* __restrict__ oh,
                                  float* __restrict__ of,
                                  int node, int lane, uint2* lwF) {
    int start = offs[node];
    int deg = offs[node + 1] - start;
    float4 ad = *(const float4*)(adst + node * 4);

    float w0, w1, w2, w3;
    float m0, m1, m2, m3, i0, i1, i2, i3;
    int msrc = 0;

    if (deg <= 64) {
        float t0 = -1e30f, t1 = -1e30f, t2 = -1e30f, t3 = -1e30f;
        if (lane < deg) {
            int sidx = csr[start + lane];
            float4 as = *(const float4*)(asrc + sidx * 4);
            t0 = lrelu02(as.x + ad.x);
            t1 = lrelu02(as.y + ad.y);
            t2 = lrelu02(as.z + ad.z);
            t3 = lrelu02(as.w + ad.w);
            msrc = sidx;
        }
        m0 = t0; m1 = t1; m2 = t2; m3 = t3;
#pragma unroll
        for (int o = 1; o < 64; o <<= 1) {
            m0 = fmaxf(m0, __shfl_xor(m0, o));
            m1 = fmaxf(m1, __shfl_xor(m1, o));
            m2 = fmaxf(m2, __shfl_xor(m2, o));
            m3 = fmaxf(m3, __shfl_xor(m3, o));
        }
        w0 = __expf(t0 - m0);
        w1 = __expf(t1 - m1);
        w2 = __expf(t2 - m2);
        w3 = __expf(t3 - m3);
        float s0 = w0, s1 = w1, s2 = w2, s3 = w3;
#pragma unroll
        for (int o = 1; o < 64; o <<= 1) {
            s0 += __shfl_xor(s0, o);
            s1 += __shfl_xor(s1, o);
            s2 += __shfl_xor(s2, o);
            s3 += __shfl_xor(s3, o);
        }
        i0 = 1.0f / (s0 + 1e-16f);
        i1 = 1.0f / (s1 + 1e-16f);
        i2 = 1.0f / (s2 + 1e-16f);
        i3 = 1.0f / (s3 + 1e-16f);
        w0 *= i0; w1 *= i1; w2 *= i2; w3 *= i3;
    } else {
        m0 = m1 = m2 = m3 = -1e30f;
        float s0 = 0.f, s1 = 0.f, s2 = 0.f, s3 = 0.f;
        float e0 = 0.f, e1 = 0.f, e2 = 0.f, e3 = 0.f;
        for (int j = lane; j < deg; j += 64) {
            int sidx = csr[start + j];
            float4 as = *(const float4*)(asrc + sidx * 4);
            float t0 = lrelu02(as.x + ad.x);
            float t1 = lrelu02(as.y + ad.y);
            float t2 = lrelu02(as.z + ad.z);
            float t3 = lrelu02(as.w + ad.w);
            if (j == lane) { e0 = t0; e1 = t1; e2 = t2; e3 = t3; msrc = sidx; }
            float nm;
            nm = fmaxf(m0, t0); s0 = s0 * __expf(m0 - nm) + __expf(t0 - nm); m0 = nm;
            nm = fmaxf(m1, t1); s1 = s1 * __expf(m1 - nm) + __expf(t1 - nm); m1 = nm;
            nm = fmaxf(m2, t2); s2 = s2 * __expf(m2 - nm) + __expf(t2 - nm); m2 = nm;
            nm = fmaxf(m3, t3); s3 = s3 * __expf(m3 - nm) + __expf(t3 - nm); m3 = nm;
        }
        for (int o = 32; o; o >>= 1) {
            float om, os, nm;
            om = __shfl_xor(m0, o); os = __shfl_xor(s0, o);
            nm = fmaxf(m0, om); s0 = s0 * __expf(m0 - nm) + os * __expf(om - nm); m0 = nm;
            om = __shfl_xor(m1, o); os = __shfl_xor(s1, o);
            nm = fmaxf(m1, om); s1 = s1 * __expf(m1 - nm) + os * __expf(om - nm); m1 = nm;
            om = __shfl_xor(m2, o); os = __shfl_xor(s2, o);
            nm = fmaxf(m2, om); s2 = s2 * __expf(m2 - nm) + os * __expf(om - nm); m2 = nm;
            om = __shfl_xor(m3, o); os = __shfl_xor(s3, o);
            nm = fmaxf(m3, om); s3 = s3 * __expf(m3 - nm) + os * __expf(om - nm); m3 = nm;
        }
        i0 = 1.0f / (s0 + 1e-16f);
        i1 = 1.0f / (s1 + 1e-16f);
        i2 = 1.0f / (s2 + 1e-16f);
        i3 = 1.0f / (s3 + 1e-16f);
        w0 = __expf(e0 - m0) * i0;
        w1 = __expf(e1 - m1) * i1;
        w2 = __expf(e2 - m2) * i2;
        w3 = __expf(e3 - m3) * i3;
    }

    lwF[lane] = (uint2){pack2h(w0, w1), pack2h(w2, w3)};

    int hp = lane >> 5;
    const uint32_t* lwu = (const uint32_t*)lwF;
    float aE0 = 0.f, aO0 = 0.f, aE1 = 0.f, aO1 = 0.f;
    float c0a = 0.f, c0b = 0.f, c1a = 0.f, c1b = 0.f;
    const uint32_t* hb = (const uint32_t*)hf2 + lane * 2;
    int jmax = deg < 64 ? deg : 64;

    int j = 0;
    if (CONCAT) {
        for (; j + 4 <= jmax; j += 4) {
            int s0 = __builtin_amdgcn_readlane(msrc, j);
            int s1 = __builtin_amdgcn_readlane(msrc, j + 1);
            int s2 = __builtin_amdgcn_readlane(msrc, j + 2);
            int s3 = __builtin_amdgcn_readlane(msrc, j + 3);
            uint2 q0 = *(const uint2*)(hb + (size_t)s0 * 128);
            uint2 q1 = *(const uint2*)(hb + (size_t)s1 * 128);
            uint2 q2 = *(const uint2*)(hb + (size_t)s2 * 128);
            uint2 q3 = *(const uint2*)(hb + (size_t)s3 * 128);
            uint32_t wA = lwu[(j + 0) * 2 + hp];
            uint32_t wB = lwu[(j + 1) * 2 + hp];
            uint32_t wC = lwu[(j + 2) * 2 + hp];
            uint32_t wD = lwu[(j + 3) * 2 + hp];
            uint32_t weAB = permb(wA, wB, SEL_E), woAB = permb(wA, wB, SEL_O);
            uint32_t weCD = permb(wC, wD, SEL_E), woCD = permb(wC, wD, SEL_O);
            uint32_t xeAB = permb(q0.x, q1.x, SEL_E), xoAB = permb(q0.x, q1.x, SEL_O);
            uint32_t yeAB = permb(q0.y, q1.y, SEL_E), yoAB = permb(q0.y, q1.y, SEL_O);
            uint32_t xeCD = permb(q2.x, q3.x, SEL_E), xoCD = permb(q2.x, q3.x, SEL_O);
            uint32_t yeCD = permb(q2.y, q3.y, SEL_E), yoCD = permb(q2.y, q3.y, SEL_O);
            aE0 = fdot2f(as_h2(xeAB), as_h2(weAB), aE0);
            aO0 = fdot2f(as_h2(xoAB), as_h2(woAB), aO0);
            aE1 = fdot2f(as_h2(yeAB), as_h2(weAB), aE1);
            aO1 = fdot2f(as_h2(yoAB), as_h2(woAB), aO1);
            aE0 = fdot2f(as_h2(xeCD), as_h2(weCD), aE0);
            aO0 = fdot2f(as_h2(xoCD), as_h2(woCD), aO0);
            aE1 = fdot2f(as_h2(yeCD), as_h2(weCD), aE1);
            aO1 = fdot2f(as_h2(yoCD), as_h2(woCD), aO1);
        }
        for (; j < jmax; j++) {
            int sidx = __builtin_amdgcn_readlane(msrc, j);
            f16x2 wh = as_h2(lwu[j * 2 + hp]);
            uint2 q = *(const uint2*)(hb + (size_t)sidx * 128);
            f16x2 qx = as_h2(q.x), qy = as_h2(q.y);
            aE0 += (float)qx[0] * (float)wh[0];
            aO0 += (float)qx[1] * (float)wh[1];
            aE1 += (float)qy[0] * (float)wh[0];
            aO1 += (float)qy[1] * (float)wh[1];
        }
    } else {
        for (; j + 4 <= jmax; j += 4) {
            int s0 = __builtin_amdgcn_readlane(msrc, j);
            int s1 = __builtin_amdgcn_readlane(msrc, j + 1);
            int s2 = __builtin_amdgcn_readlane(msrc, j + 2);
            int s3 = __builtin_amdgcn_readlane(msrc, j + 3);
            uint2 q0 = *(const uint2*)(hb + (size_t)s0 * 128);
            uint2 q1 = *(const uint2*)(hb + (size_t)s1 * 128);
            uint2 q2 = *(const uint2*)(hb + (size_t)s2 * 128);
            uint2 q3 = *(const uint2*)(hb + (size_t)s3 * 128);
            f16x2 w0v = as_h2(lwu[(j + 0) * 2 + hp]);
            f16x2 w1v = as_h2(lwu[(j + 1) * 2 + hp]);
            f16x2 w2v = as_h2(lwu[(j + 2) * 2 + hp]);
            f16x2 w3v = as_h2(lwu[(j + 3) * 2 + hp]);
            c0a = fdot2f(as_h2(q0.x), w0v, c0a);
            c1a = fdot2f(as_h2(q0.y), w0v, c1a);
            c0b = fdot2f(as_h2(q1.x), w1v, c0b);
            c1b = fdot2f(as_h2(q1.y), w1v, c1b);
            c0a = fdot2f(as_h2(q2.x), w2v, c0a);
            c1a = fdot2f(as_h2(q2.y), w2v, c1a);
            c0b = fdot2f(as_h2(q3.x), w3v, c0b);
            c1b = fdot2f(as_h2(q3.y), w3v, c1b);
        }
        for (; j < jmax; j++) {
            int sidx = __builtin_amdgcn_readlane(msrc, j);
            f16x2 wh = as_h2(lwu[j * 2 + hp]);
            uint2 q = *(const uint2*)(hb + (size_t)sidx * 128);
            c0a = fdot2f(as_h2(q.x), wh, c0a);
            c1a = fdot2f(as_h2(q.y), wh, c1a);
        }
    }
    for (int jj = 64; jj < deg; jj++) {
        int sidx = csr[start + jj];
        float4 as = *(const float4*)(asrc + sidx * 4);
        float u0 = __expf(lrelu02(as.x + ad.x) - m0) * i0;
        float u1 = __expf(lrelu02(as.y + ad.y) - m1) * i1;
        float u2 = __expf(lrelu02(as.z + ad.z) - m2) * i2;
        float u3 = __expf(lrelu02(as.w + ad.w) - m3) * i3;
        float ue = hp ? u2 : u0;
        float uo = hp ? u3 : u1;
        uint2 q = *(const uint2*)(hb + (size_t)sidx * 128);
        float xl, xh2, yl, yh;
        h2_unpack(q.x, xl, xh2);
        h2_unpack(q.y, yl, yh);
        if (CONCAT) {
            aE0 += ue * xl;
            aO0 += uo * xh2;
            aE1 += ue * yl;
            aO1 += uo * yh;
        } else {
            c0a += ue * xl + uo * xh2;
            c1a += ue * yl + uo * yh;
        }
    }

    int c0 = (lane & 31) * 2;
    int he = hp * 2, ho = hp * 2 + 1;
    if (CONCAT) {
        size_t base = (size_t)node * HC;
        float vE0 = elu1(aE0 + bias[he * 64 + c0]);
        float vE1 = elu1(aE1 + bias[he * 64 + c0 + 1]);
        float vO0 = elu1(aO0 + bias[ho * 64 + c0]);
        float vO1 = elu1(aO1 + bias[ho * 64 + c0 + 1]);
        f16 pe[2] = {(f16)vE0, (f16)vE1};
        f16 po[2] = {(f16)vO0, (f16)vO1};
        *(uint32_t*)(oh + base + he * 64 + c0) = *(const uint32_t*)pe;
        *(uint32_t*)(oh + base + ho * 64 + c0) = *(const uint32_t*)po;
    } else {
        float s0 = c0a + c0b;
        float s1 = c1a + c1b;
        s0 += __shfl_xor(s0, 32);
        s1 += __shfl_xor(s1, 32);
        if (hp == 0) {
            int g = gb[node];
            atomicAdd(of + g * 64 + c0, 0.25f * s0);
            atomicAdd(of + g * 64 + c0 + 1, 0.25f * s1);
        }
    }
}

// ---------------------------------------------------------------------------
// GAT aggregation (R20 structure, unchanged — at the L3 gather service floor):
// two nodes/wave, double-buffered pipeline, fused mean-pool via block-level
// LDS reduction + 16-replica spreading.
// ---------------------------------------------------------------------------
template <int CONCAT>
__global__ __launch_bounds__(256, 4) void gat_agg(const ushort_t* __restrict__ hf2,
                                                  const float* __restrict__ asrc,
                                                  const float* __restrict__ adst,
                                                  const int* __restrict__ offs,
                                                  const int* __restrict__ csr,
                                                  const int* __restrict__ gb,
                                                  const float* __restrict__ bias,
                                                  f16* __restrict__ oh,
                                                  float* __restrict__ of) {
    __shared__ uint4 lw4[4][64];   // [wave][grp*32 + j] = {src, w01, src, w23}
    __shared__ float part[2][64];  // CONCAT=0: block pool partials
    __shared__ int oks[4];         // CONCAT=0: per-wave fast-path vote
    int wave = threadIdx.x >> 6, lane = threadIdx.x & 63;
    int grp = lane >> 5, l31 = lane & 31;
    int hp = (lane >> 4) & 1;      // head pair within group
    int nbase = blockIdx.x * 8 + wave * 2;   // NN % 8 == 0: always in range
    int node = nbase + grp;
    int start = offs[node];
    int deg = offs[node + 1] - start;

    // replica-adjusted pool base (CONCAT=0 only; harmless otherwise)
    float* ofr = of + (size_t)(blockIdx.x & (NREP - 1)) * NG * 64;

    bool ok = __all(deg <= 32);
    bool useLds = false;
    int g_first = 0, g_last = 0;
    if (!CONCAT) {
        // block-uniform vote BEFORE any divergent return (barrier safety)
        if (threadIdx.x < 128) ((float*)part)[threadIdx.x] = 0.f;
        if (lane == 0) oks[wave] = ok ? 1 : 0;
        __syncthreads();
        useLds = oks[0] && oks[1] && oks[2] && oks[3];
        g_first = gb[blockIdx.x * 8];
        g_last  = gb[blockIdx.x * 8 + 7];
    }

    if (!ok) {
        // rare fallback: full wave per node, sequentially (direct atomics)
        uint2* lwF = (uint2*)&lw4[wave][0];
        gat_node_fullwave<CONCAT>(hf2, asrc, adst, offs, csr, gb, bias, oh, ofr,
                                  nbase, lane, lwF);
        gat_node_fullwave<CONCAT>(hf2, asrc, adst, offs, csr, gb, bias, oh, ofr,
                                  nbase + 1, lane, lwF);
        return;
    }

    // ---------- prologue: csr read, then EARLY batch-0/1 row loads ----------
    const uint4* hq = (const uint4*)hf2;   // hf2 row = 32 uint4
    int msrc = 0;
    bool act = l31 < deg;
    if (act) msrc = csr[start + l31];

    int b0 = grp * 32;
    int i0 = __shfl(msrc, b0 + 0);
    int i1 = __shfl(msrc, b0 + 1);
    int i2 = __shfl(msrc, b0 + 2);
    int i3 = __shfl(msrc, b0 + 3);
    int i4 = __shfl(msrc, b0 + 4);
    int i5 = __shfl(msrc, b0 + 5);
    int i6 = __shfl(msrc, b0 + 6);
    int i7 = __shfl(msrc, b0 + 7);
    uint4 q0 = hq[(uint32_t)i0 * 32u + l31];
    uint4 q1 = hq[(uint32_t)i1 * 32u + l31];
    uint4 q2 = hq[(uint32_t)i2 * 32u + l31];
    uint4 q3 = hq[(uint32_t)i3 * 32u + l31];
    uint4 r0 = hq[(uint32_t)i4 * 32u + l31];
    uint4 r1 = hq[(uint32_t)i5 * 32u + l31];
    uint4 r2 = hq[(uint32_t)i6 * 32u + l31];
    uint4 r3 = hq[(uint32_t)i7 * 32u + l31];

    // ---------- softmax over the 32-lane group (deg <= 32) ----------
    float4 ad = *(const float4*)(adst + (size_t)node * 4);
    float t0 = -1e30f, t1 = -1e30f, t2 = -1e30f, t3 = -1e30f;
    if (act) {
        float4 as = *(const float4*)(asrc + (size_t)msrc * 4);
        t0 = lrelu02(as.x + ad.x);
        t1 = lrelu02(as.y + ad.y);
        t2 = lrelu02(as.z + ad.z);
        t3 = lrelu02(as.w + ad.w);
    }
    float m0 = t0, m1 = t1, m2 = t2, m3 = t3;
#pragma unroll
    for (int o = 1; o < 32; o <<= 1) {
        m0 = fmaxf(m0, __shfl_xor(m0, o));
        m1 = fmaxf(m1, __shfl_xor(m1, o));
        m2 = fmaxf(m2, __shfl_xor(m2, o));
        m3 = fmaxf(m3, __shfl_xor(m3, o));
    }
    float w0 = __expf(t0 - m0);
    float w1 = __expf(t1 - m1);
    float w2 = __expf(t2 - m2);
    float w3 = __expf(t3 - m3);
    float s0 = w0, s1 = w1, s2 = w2, s3 = w3;
#pragma unroll
    for (int o = 1; o < 32; o <<= 1) {
        s0 += __shfl_xor(s0, o);
        s1 += __shfl_xor(s1, o);
        s2 += __shfl_xor(s2, o);
        s3 += __shfl_xor(s3, o);
    }
    w0 *= 1.0f / (s0 + 1e-16f);
    w1 *= 1.0f / (s1 + 1e-16f);
    w2 *= 1.0f / (s2 + 1e-16f);
    w3 *= 1.0f / (s3 + 1e-16f);

    // park per-edge entry (wave-private LDS; no barrier). pad lanes: w=0.
    lw4[wave][lane] = (uint4){(uint32_t)msrc, pack2h(w0, w1),
                              (uint32_t)msrc, pack2h(w2, w3)};

    const uint2* lwp = (const uint2*)&lw4[wave][grp * 32];  // entry j half hp
    int c0 = (l31 & 15) * 4;
    int deg4 = (deg + 3) & ~3;     // >= 4 (self-loop guarantees deg >= 1)

    // weights for batches 0 (q) and 1 (r), this lane's head pair
    uint32_t wy0 = lwp[0 * 2 + hp].y;
    uint32_t wy1 = lwp[1 * 2 + hp].y;
    uint32_t wy2 = lwp[2 * 2 + hp].y;
    uint32_t wy3 = lwp[3 * 2 + hp].y;
    uint32_t wz0 = lwp[4 * 2 + hp].y;
    uint32_t wz1 = lwp[5 * 2 + hp].y;
    uint32_t wz2 = lwp[6 * 2 + hp].y;
    uint32_t wz3 = lwp[7 * 2 + hp].y;

    if (CONCAT) {
        float aE0 = 0.f, aE1 = 0.f, aE2 = 0.f, aE3 = 0.f;
        float aO0 = 0.f, aO1 = 0.f, aO2 = 0.f, aO3 = 0.f;
#define CPAIR(A0, A1, W0, W1)                                                  \
        {                                                                      \
            uint32_t we = permb(W0, W1, SEL_E);                                \
            uint32_t wo = permb(W0, W1, SEL_O);                                \
            aE0 = fdot2f(as_h2(permb(A0.x, A1.x, SEL_E)), as_h2(we), aE0);     \
            aO0 = fdot2f(as_h2(permb(A0.x, A1.x, SEL_O)), as_h2(wo), aO0);     \
            aE1 = fdot2f(as_h2(permb(A0.y, A1.y, SEL_E)), as_h2(we), aE1);     \
            aO1 = fdot2f(as_h2(permb(A0.y, A1.y, SEL_O)), as_h2(wo), aO1);     \
            aE2 = fdot2f(as_h2(permb(A0.z, A1.z, SEL_E)), as_h2(we), aE2);     \
            aO2 = fdot2f(as_h2(permb(A0.z, A1.z, SEL_O)), as_h2(wo), aO2);     \
            aE3 = fdot2f(as_h2(permb(A0.w, A1.w, SEL_E)), as_h2(we), aE3);     \
            aO3 = fdot2f(as_h2(permb(A0.w, A1.w, SEL_O)), as_h2(wo), aO3);     \
        }
        int j = 0;
        for (;;) {
            // ---- compute q batch (edges j..j+3), prefetch j+8..j+11 -> q ----
            CPAIR(q0, q1, wy0, wy1)
            CPAIR(q2, q3, wy2, wy3)
            {
                int p = j + 8;
                if (p < deg4) {
                    uint2 n0 = lwp[(p + 0) * 2 + hp];
                    uint2 n1 = lwp[(p + 1) * 2 + hp];
                    uint2 n2 = lwp[(p + 2) * 2 + hp];
                    uint2 n3 = lwp[(p + 3) * 2 + hp];
                    wy0 = n0.y; wy1 = n1.y; wy2 = n2.y; wy3 = n3.y;
                    q0 = hq[n0.x * 32u + l31];
                    q1 = hq[n1.x * 32u + l31];
                    q2 = hq[n2.x * 32u + l31];
                    q3 = hq[n3.x * 32u + l31];
                }
            }
            j += 4;
            if (j >= deg4) break;
            // ---- compute r batch (edges j..j+3), prefetch j+8..j+11 -> r ----
            CPAIR(r0, r1, wz0, wz1)
            CPAIR(r2, r3, wz2, wz3)
            {
                int p = j + 8;
                if (p < deg4) {
                    uint2 n0 = lwp[(p + 0) * 2 + hp];
                    uint2 n1 = lwp[(p + 1) * 2 + hp];
                    uint2 n2 = lwp[(p + 2) * 2 + hp];
                    uint2 n3 = lwp[(p + 3) * 2 + hp];
                    wz0 = n0.y; wz1 = n1.y; wz2 = n2.y; wz3 = n3.y;
                    r0 = hq[n0.x * 32u + l31];
                    r1 = hq[n1.x * 32u + l31];
                    r2 = hq[n2.x * 32u + l31];
                    r3 = hq[n3.x * 32u + l31];
                }
            }
            j += 4;
            if (j >= deg4) break;
        }
#undef CPAIR
        // heads stay separate: lane writes 4 channels x (even,odd) heads
        int he = hp * 2, ho = hp * 2 + 1;
        size_t base = (size_t)node * HC;
        float4 bE = *(const float4*)(bias + he * 64 + c0);
        float4 bO = *(const float4*)(bias + ho * 64 + c0);
        f16 pe[4] = {(f16)elu1(aE0 + bE.x), (f16)elu1(aE1 + bE.y),
                     (f16)elu1(aE2 + bE.z), (f16)elu1(aE3 + bE.w)};
        f16 po[4] = {(f16)elu1(aO0 + bO.x), (f16)elu1(aO1 + bO.y),
                     (f16)elu1(aO2 + bO.z), (f16)elu1(aO3 + bO.w)};
        *(uint2*)(oh + base + he * 64 + c0) = *(const uint2*)pe;
        *(uint2*)(oh + base + ho * 64 + c0) = *(const uint2*)po;
    } else {
        float a0 = 0.f, a1 = 0.f, a2 = 0.f, a3 = 0.f;
        float b0f = 0.f, b1f = 0.f, b2f = 0.f, b3f = 0.f;
        int j = 0;
        for (;;) {
            // ---- compute q batch, prefetch j+8 -> q ----
            {
                f16x2 wvA = as_h2(wy0), wvB = as_h2(wy1);
                f16x2 wvC = as_h2(wy2), wvD = as_h2(wy3);
                a0 = fdot2f(as_h2(q0.x), wvA, a0);
                a1 = fdot2f(as_h2(q0.y), wvA, a1);
                a2 = fdot2f(as_h2(q0.z), wvA, a2);
                a3 = fdot2f(as_h2(q0.w), wvA, a3);
                b0f = fdot2f(as_h2(q1.x), wvB, b0f);
                b1f = fdot2f(as_h2(q1.y), wvB, b1f);
                b2f = fdot2f(as_h2(q1.z), wvB, b2f);
                b3f = fdot2f(as_h2(q1.w), wvB, b3f);
                a0 = fdot2f(as_h2(q2.x), wvC, a0);
                a1 = fdot2f(as_h2(q2.y), wvC, a1);
                a2 = fdot2f(as_h2(q2.z), wvC, a2);
                a3 = fdot2f(as_h2(q2.w), wvC, a3);
                b0f = fdot2f(as_h2(q3.x), wvD, b0f);
                b1f = fdot2f(as_h2(q3.y), wvD, b1f);
                b2f = fdot2f(as_h2(q3.z), wvD, b2f);
                b3f = fdot2f(as_h2(q3.w), wvD, b3f);
            }
            {
                int p = j + 8;
                if (p < deg4) {
                    uint2 n0 = lwp[(p + 0) * 2 + hp];
                    uint2 n1 = lwp[(p + 1) * 2 + hp];
                    uint2 n2 = lwp[(p + 2) * 2 + hp];
                    uint2 n3 = lwp[(p + 3) * 2 + hp];
                    wy0 = n0.y; wy1 = n1.y; wy2 = n2.y; wy3 = n3.y;
                    q0 = hq[n0.x * 32u + l31];
                    q1 = hq[n1.x * 32u + l31];
                    q2 = hq[n2.x * 32u + l31];
                    q3 = hq[n3.x * 32u + l31];
                }
            }
            j += 4;
            if (j >= deg4) break;
            // ---- compute r batch, prefetch j+8 -> r ----
            {
                f16x2 wvA = as_h2(wz0), wvB = as_h2(wz1);
                f16x2 wvC = as_h2(wz2), wvD = as_h2(wz3);
                a0 = fdot2f(as_h2(r0.x), wvA, a0);
                a1 = fdot2f(as_h2(r0.y), wvA, a1);
                a2 = fdot2f(as_h2(r0.z), wvA, a2);
                a3 = fdot2f(as_h2(r0.w), wvA, a3);
                b0f = fdot2f(as_h2(r1.x), wvB, b0f);
                b1f = fdot2f(as_h2(r1.y), wvB, b1f);
                b2f = fdot2f(as_h2(r1.z), wvB, b2f);
                b3f = fdot2f(as_h2(r1.w), wvB, b3f);
                a0 = fdot2f(as_h2(r2.x), wvC, a0);
                a1 = fdot2f(as_h2(r2.y), wvC, a1);
                a2 = fdot2f(as_h2(r2.z), wvC, a2);
                a3 = fdot2f(as_h2(r2.w), wvC, a3);
                b0f = fdot2f(as_h2(r3.x), wvD, b0f);
                b1f = fdot2f(as_h2(r3.y), wvD, b1f);
                b2f = fdot2f(as_h2(r3.z), wvD, b2f);
                b3f = fdot2f(as_h2(r3.w), wvD, b3f);
            }
            {
                int p = j + 8;
                if (p < deg4) {
                    uint2 n0 = lwp[(p + 0) * 2 + hp];
                    uint2 n1 = lwp[(p + 1) * 2 + hp];
                    uint2 n2 = lwp[(p + 2) * 2 + hp];
                    uint2 n3 = lwp[(p + 3) * 2 + hp];
                    wz0 = n0.y; wz1 = n1.y; wz2 = n2.y; wz3 = n3.y;
                    r0 = hq[n0.x * 32u + l31];
                    r1 = hq[n1.x * 32u + l31];
                    r2 = hq[n2.x * 32u + l31];
                    r3 = hq[n3.x * 32u + l31];
                }
            }
            j += 4;
            if (j >= deg4) break;
        }
        // head-pair sum is in each dot2; add the other hp via shfl_xor(16)
        float u0 = a0 + b0f, u1 = a1 + b1f, u2 = a2 + b2f, u3 = a3 + b3f;
        u0 += __shfl_xor(u0, 16);
        u1 += __shfl_xor(u1, 16);
        u2 += __shfl_xor(u2, 16);
        u3 += __shfl_xor(u3, 16);
        float o0 = 0.25f * u0, o1 = 0.25f * u1, o2 = 0.25f * u2, o3 = 0.25f * u3;
        int g = gb[node];
        if (hp == 0) {
            bool inLds = useLds && (g == g_first || g == g_last);
            if (inLds) {
                int slot = (g != g_first) ? 1 : 0;
                atomicAdd(&part[slot][c0 + 0], o0);
                atomicAdd(&part[slot][c0 + 1], o1);
                atomicAdd(&part[slot][c0 + 2], o2);
                atomicAdd(&part[slot][c0 + 3], o3);
            } else {
                float* pb = ofr + g * 64 + c0;
                atomicAdd(pb + 0, o0);
                atomicAdd(pb + 1, o1);
                atomicAdd(pb + 2, o2);
                atomicAdd(pb + 3, o3);
            }
        }
        if (useLds) {
            __syncthreads();   // block-uniform: all 4 waves on fast path
            int t = threadIdx.x;
            if (t < 64) {
                atomicAdd(ofr + g_first * 64 + t, part[0][t]);
            } else if (t < 128 && g_last != g_first) {
                atomicAdd(ofr + g_last * 64 + (t - 64), part[1][t - 64]);
            }
        }
    }
}

// ---------------------------------------------------------------------------
// fc: sums the NREP pool replicas; cnt via binary search over sorted batch;
// bias b2 folded in: pooled_c = (sum_r pool[r][g][c])/cnt + b2[c].
// ---------------------------------------------------------------------------
__global__ void fc_kernel(const float* __restrict__ pool,
                          const int* __restrict__ batch,
                          const float* __restrict__ b2,
                          const float* __restrict__ fc_w, const float* __restrict__ fc_b,
                          float* __restrict__ out) {
    int idx = blockIdx.x * blockDim.x + threadIdx.x;
    if (idx >= NG * NOUT) return;
    int g = idx >> 3, o = idx & 7;
    int lo = 0, hi = NN;
    while (lo < hi) { int mid = (lo + hi) >> 1; if (batch[mid] < g) lo = mid + 1; else hi = mid; }
    int lo2 = lo, hi2 = NN;
    while (lo2 < hi2) { int mid = (lo2 + hi2) >> 1; if (batch[mid] < g + 1) lo2 = mid + 1; else hi2 = mid; }
    float inv = 1.0f / fmaxf((float)(lo2 - lo), 1.0f);
    float s = 0.f;
#pragma unroll
    for (int c = 0; c < 64; c++) {
        float v = 0.f;
#pragma unroll
        for (int r = 0; r < NREP; r++) v += pool[((size_t)r * NG + g) * 64 + c];
        s += (v * inv + b2[c]) * fc_w[c * 8 + o];
    }
    out[idx] = s + fc_b[o];
}

// ---------------------------------------------------------------------------
extern "C" void kernel_launch(void* const* d_in, const int* in_sizes, int n_in,
                              void* d_out, int out_size, void* d_ws, size_t ws_size,
                              hipStream_t stream) {
    const float* x    = (const float*)d_in[0];
    const int*   ei   = (const int*)d_in[1];   // [2, E]
    const int*   batch= (const int*)d_in[2];
    const float* W1   = (const float*)d_in[3];
    const float* a1s  = (const float*)d_in[4];
    const float* a1d  = (const float*)d_in[5];
    const float* b1   = (const float*)d_in[6];
    const float* W2   = (const float*)d_in[7];
    const float* a2s  = (const float*)d_in[8];
    const float* a2d  = (const float*)d_in[9];
    const float* b2   = (const float*)d_in[10];
    const float* fc_w = (const float*)d_in[11];
    const float* fc_b = (const float*)d_in[12];
    float* out = (float*)d_out;

    char* p = (char*)d_ws;
    auto alloc = [&](size_t bytes) -> char* {
        char* r = p; p += (bytes + 255) & ~(size_t)255; return r;
    };
    int*   deg     = (int*)alloc((size_t)NN * 4);
    float* pool    = (float*)alloc((size_t)NREP * NG * 64 * 4);
    size_t zero_bytes = (size_t)(p - (char*)d_ws);
    int*   offs    = (int*)alloc((size_t)(NN + 1) * 4);
    int*   partials= (int*)alloc(64 * 4);
    int*   csr     = (int*)alloc((size_t)EP * 4);
    int*   rank    = (int*)alloc((size_t)EP * 4);
    float* asrc    = (float*)alloc((size_t)NN * 4 * 4);
    float* adst    = (float*)alloc((size_t)NN * 4 * 4);
    ushort_t* hf2  = (ushort_t*)alloc((size_t)MPAD * HC * 2); // packed fp16 h
    f16*   xh      = (f16*)alloc((size_t)MPAD * F_IN * 2);
    f16*   act     = (f16*)alloc((size_t)MPAD * HC * 2);
    f16*   w1t     = (f16*)alloc((size_t)HC * F_IN * 2);      // [256][128]
    f16*   w2t     = (f16*)alloc((size_t)HC * HC * 2);        // [256][256]

    hipMemsetAsync(d_ws, 0, zero_bytes, stream);

    // fused prep: edge hist (rank-recording) + fp16 conversions
    int prep_n = EP + XN4 + NW;
    prep_kernel<<<(prep_n + 255) / 256, 256, 0, stream>>>(
        ei + NE, x, W1, W2, deg, rank, xh, w1t, w2t);
    scan_p1<<<49, 256, 0, stream>>>(deg, partials);
    scan_p3<<<49, 256, 0, stream>>>(deg, partials, offs);

    int gemmB = ((NN + 127) / 128) * 2;          // 782 (x-tile pairs: by = bid&1)
    int fillB = (EP + 255) / 256;                // 3321 edge_fill tail blocks
    int nb8 = (NN + 7) / 8;                      // 2 nodes/wave * 4 waves/block

    // layer 1 GEMM + fused edge_fill tail (independent work, same dispatch)
    gemm_gat<<<gemmB + fillB, 256, 0, stream>>>(
        xh, w1t, a1s, a1d, hf2, asrc, adst, NN, F_IN, gemmB,
        ei, ei + NE, offs, rank, csr);
    gat_agg<1><<<nb8, 256, 0, stream>>>(hf2, asrc, adst, offs, csr, batch, b1, act, nullptr);
    // layer 2
    gemm_gat<<<gemmB, 256, 0, stream>>>(
        act, w2t, a2s, a2d, hf2, asrc, adst, NN, HC, gemmB,
        ei, ei + NE, offs, rank, csr);
    gat_agg<0><<<nb8, 256, 0, stream>>>(hf2, asrc, adst, offs, csr, batch, b2, nullptr, pool);
    // readout (replica sum + cnt binary search + b2 fold)
    fc_kernel<<<(NG * NOUT + 255) / 256, 256, 0, stream>>>(pool, batch, b2, fc_w, fc_b, out);
}